// Round 4
// baseline (1906.864 us; speedup 1.0000x reference)
//
#include <hip/hip_runtime.h>
#include <hip/hip_bf16.h>

typedef __hip_bfloat16 bf16;

#define T_SEQ 4096
#define NEMBD 2048
#define QKVD  3072
#define QDIM  2048
#define DKV   1024
#define KDIM  512
#define NH    16
#define DH    128
#define NST   16
#define DTR   64
#define WIN   512
#define NCHUNK 64
#define CLEN   64

__device__ inline float bf2f(bf16 x) { return __bfloat162float(x); }

struct F8 { float v[8]; };

// load 8 contiguous bf16 (16B) and widen to fp32 (bf16 bits << 16)
__device__ inline F8 load_b8(const bf16* p) {
  union { uint4 q; unsigned short s[8]; } u;
  u.q = *reinterpret_cast<const uint4*>(p);
  F8 r;
#pragma unroll
  for (int i = 0; i < 8; i++) r.v[i] = __uint_as_float((unsigned)u.s[i] << 16);
  return r;
}

// load 8 elements [idx, idx+8) from an INPUT array whose real dtype is
// bf16 (f32flag=0) or fp32 (f32flag=1). idx must be a multiple of 4.
__device__ inline F8 load8(const void* base, size_t idx, int f32flag) {
  if (f32flag) {
    const float4* p = reinterpret_cast<const float4*>((const float*)base + idx);
    float4 a = p[0], b = p[1];
    F8 r;
    r.v[0]=a.x; r.v[1]=a.y; r.v[2]=a.z; r.v[3]=a.w;
    r.v[4]=b.x; r.v[5]=b.y; r.v[6]=b.z; r.v[7]=b.w;
    return r;
  }
  return load_b8((const bf16*)base + idx);
}

__device__ inline float load1(const void* base, size_t idx, int f32flag) {
  return f32flag ? ((const float*)base)[idx] : bf2f(((const bf16*)base)[idx]);
}

__device__ inline unsigned short f2b_bits(float f) {
  bf16 h = __float2bfloat16(f);  // RNE
  union { bf16 h; unsigned short u; } c; c.h = h; return c.u;
}

__device__ inline ushort4 pack4(float a, float b, float c, float d) {
  ushort4 r; r.x = f2b_bits(a); r.y = f2b_bits(b); r.z = f2b_bits(c); r.w = f2b_bits(d);
  return r;
}

// ---------------------------------------------------------------------------
// Input-dtype detection (round-1/2 evidence: fp32; keep the hedge, zero cost).
// flag: 0 = inputs bf16, 1 = inputs fp32.
// ---------------------------------------------------------------------------
__global__ void detect_dtype(const unsigned short* __restrict__ x, int* __restrict__ flag) {
  if (threadIdx.x == 0 && blockIdx.x == 0) {
    int c = 0;
    for (int i = 0; i < 128; i++) {
      float v = __uint_as_float((unsigned)x[i] << 16);
      float a = fabsf(v);
      if (a >= 1e-8f && a <= 1e4f) c++;   // NaN/Inf fail both compares
    }
    flag[0] = (c >= 120) ? 0 : 1;
  }
}

// ---------------------------------------------------------------------------
// GEMM: C[M,N] = A[M,K] * B[N,K]^T, fp32 accumulate.
// amode/bmode: 0 = bf16, 1 = fp32, 2 = resolve from *dflag at runtime.
// mode 0: cols <2048 -> oq (bf16 [M,2048]), cols >=2048 -> ou (bf16 [M,1024])
// mode 1: FP32 out oc [M,N]   <-- round-4 change: output dtype is float32
// 128x128 tile, BK=16, 256 threads, 8x8 per thread, k-major LDS.
// ---------------------------------------------------------------------------
__global__ __launch_bounds__(256) void gemm_bt(
    const void* __restrict__ A, const void* __restrict__ B,
    const int* __restrict__ dflag, int amode, int bmode,
    int M, int N, int K, int mode,
    bf16* __restrict__ oq, bf16* __restrict__ ou, float* __restrict__ oc)
{
  __shared__ float As[16][128];
  __shared__ float Bs[16][128];
  const int af = (amode == 2) ? dflag[0] : amode;
  const int bf = (bmode == 2) ? dflag[0] : bmode;
  const int tid = threadIdx.x;
  const int bm = blockIdx.y * 128, bn = blockIdx.x * 128;
  const int ty = tid >> 4, tx = tid & 15;
  const int lrow = tid >> 1, lk8 = (tid & 1) * 8;

  float acc[8][8];
#pragma unroll
  for (int i = 0; i < 8; i++)
#pragma unroll
    for (int j = 0; j < 8; j++) acc[i][j] = 0.f;

  const size_t abase = (size_t)(bm + lrow) * K + lk8;
  const size_t bbase = (size_t)(bn + lrow) * K + lk8;

  for (int k0 = 0; k0 < K; k0 += 16) {
    F8 a = load8(A, abase + k0, af);
    F8 b = load8(B, bbase + k0, bf);
#pragma unroll
    for (int j = 0; j < 8; j++) As[lk8 + j][lrow] = a.v[j];
#pragma unroll
    for (int j = 0; j < 8; j++) Bs[lk8 + j][lrow] = b.v[j];
    __syncthreads();
#pragma unroll
    for (int kk = 0; kk < 16; kk++) {
      float4 a0 = *(const float4*)&As[kk][ty * 4];
      float4 a1 = *(const float4*)&As[kk][64 + ty * 4];
      float4 b0 = *(const float4*)&Bs[kk][tx * 4];
      float4 b1 = *(const float4*)&Bs[kk][64 + tx * 4];
      float av[8] = {a0.x, a0.y, a0.z, a0.w, a1.x, a1.y, a1.z, a1.w};
      float bv[8] = {b0.x, b0.y, b0.z, b0.w, b1.x, b1.y, b1.z, b1.w};
#pragma unroll
      for (int i = 0; i < 8; i++)
#pragma unroll
        for (int j = 0; j < 8; j++)
          acc[i][j] = fmaf(av[i], bv[j], acc[i][j]);
    }
    __syncthreads();
  }

#pragma unroll
  for (int i = 0; i < 8; i++) {
    int r = (i < 4) ? (ty * 4 + i) : (64 + ty * 4 + (i - 4));
    int gr = bm + r;
#pragma unroll
    for (int jh = 0; jh < 2; jh++) {
      int c0 = (jh == 0) ? (tx * 4) : (64 + tx * 4);
      int gc = bn + c0;
      float v0 = acc[i][jh * 4 + 0], v1 = acc[i][jh * 4 + 1];
      float v2 = acc[i][jh * 4 + 2], v3 = acc[i][jh * 4 + 3];
      if (mode == 0) {
        if (gc < QDIM) {
          *reinterpret_cast<ushort4*>(oq + (size_t)gr * QDIM + gc) = pack4(v0, v1, v2, v3);
        } else {
          *reinterpret_cast<ushort4*>(ou + (size_t)gr * DKV + (gc - QDIM)) = pack4(v0, v1, v2, v3);
        }
      } else {
        float4 f; f.x = v0; f.y = v1; f.z = v2; f.w = v3;
        *reinterpret_cast<float4*>(oc + (size_t)gr * N + gc) = f;
      }
    }
  }
}

// ---------------------------------------------------------------------------
// x_dbl[t,e] = dot(u[t,:1024], x_proj_w[e,:1024]),  e in [0,96)
// ---------------------------------------------------------------------------
__global__ __launch_bounds__(128) void xdbl_kernel(
    const bf16* __restrict__ u, const void* __restrict__ xpw,
    const int* __restrict__ dflag, float* __restrict__ xd)
{
  __shared__ float us[DKV];
  const int t = blockIdx.x, tid = threadIdx.x;
  const int f = dflag[0];
  const bf16* ur = u + (size_t)t * DKV;
  for (int i = tid; i < DKV; i += 128) us[i] = bf2f(ur[i]);
  __syncthreads();
  if (tid < 96) {
    float acc = 0.f;
    const size_t wb = (size_t)tid * DKV;
    for (int k = 0; k < DKV; k += 8) {
      F8 w = load8(xpw, wb + k, f);
#pragma unroll
      for (int j = 0; j < 8; j++) acc = fmaf(w.v[j], us[k + j], acc);
    }
    xd[(size_t)t * 96 + tid] = acc;
  }
}

// ---------------------------------------------------------------------------
// delta[t,d] = softplus(dot(x_dbl[t,0:64], dt_proj_w[d,:]) + dt_proj_b[d])
// ---------------------------------------------------------------------------
__global__ __launch_bounds__(256) void delta_kernel(
    const float* __restrict__ xd, const void* __restrict__ dtw,
    const void* __restrict__ dtb, const int* __restrict__ dflag,
    bf16* __restrict__ delta)
{
  __shared__ float dts[DTR];
  const int t = blockIdx.x, tid = threadIdx.x;
  const int f = dflag[0];
  if (tid < DTR) dts[tid] = xd[(size_t)t * 96 + tid];
  __syncthreads();
  for (int d = tid; d < DKV; d += 256) {
    float acc = load1(dtb, d, f);
    const size_t wb = (size_t)d * DTR;
#pragma unroll
    for (int k = 0; k < DTR; k += 8) {
      F8 w = load8(dtw, wb + k, f);
#pragma unroll
      for (int j = 0; j < 8; j++) acc = fmaf(w.v[j], dts[k + j], acc);
    }
    float sp = fmaxf(acc, 0.f) + log1pf(expf(-fabsf(acc)));  // stable softplus
    delta[(size_t)t * DKV + d] = __float2bfloat16(sp);
  }
}

// ---------------------------------------------------------------------------
// Scan pass1: per (chunk c, d, n): P = prod(a_t), Hl = local scan from h=0
// gid layout: c = gid>>14, d = (gid>>4)&1023, n = gid&15
// ---------------------------------------------------------------------------
__global__ __launch_bounds__(256) void scan_pass1(
    const bf16* __restrict__ delta, const bf16* __restrict__ u,
    const float* __restrict__ xd, const void* __restrict__ A_log,
    const int* __restrict__ dflag, float* __restrict__ Pb, float* __restrict__ Hl)
{
  const int gid = blockIdx.x * 256 + threadIdx.x;
  const int c = gid >> 14;
  const int r = gid & 16383;
  const int d = r >> 4, n = r & 15;
  const int f = dflag[0];
  const float A = -expf(load1(A_log, d * NST + n, f));
  float p = 1.f, h = 0.f;
  const int t0 = c * CLEN;
  for (int tt = 0; tt < CLEN; tt++) {
    int t = t0 + tt;
    float dl = bf2f(delta[(size_t)t * DKV + d]);
    float uu = bf2f(u[(size_t)t * DKV + d]);
    float bm = xd[(size_t)t * 96 + DTR + n];
    float a = expf(dl * A);
    h = a * h + dl * bm * uu;
    p *= a;
  }
  Pb[gid] = p;
  Hl[gid] = h;
}

// in-place: Pb becomes Hin (chunk-entry state)
__global__ __launch_bounds__(256) void scan_combine(
    float* __restrict__ Pb, const float* __restrict__ Hl)
{
  const int idx = blockIdx.x * 256 + threadIdx.x;  // 0..16383
  float run = 0.f;
  for (int c = 0; c < NCHUNK; c++) {
    size_t off = (size_t)c * 16384 + idx;
    float p = Pb[off], hl = Hl[off];
    Pb[off] = run;              // Hin[c] = state at chunk entry
    run = p * run + hl;
  }
}

// pass2: recompute with correct h_init, reduce y over n (16 lanes), add D*u.
// kvs is written IN-PLACE over u (safe: u[t,d] read only by this 16-lane
// group, in the same iteration, before the lane-0 store).
__global__ __launch_bounds__(256) void scan_pass2(
    const bf16* __restrict__ delta, bf16* __restrict__ u,
    const float* __restrict__ xd, const void* __restrict__ A_log,
    const void* __restrict__ Dp, const int* __restrict__ dflag,
    const float* __restrict__ Hin)
{
  const int gid = blockIdx.x * 256 + threadIdx.x;
  const int c = gid >> 14;
  const int r = gid & 16383;
  const int d = r >> 4, n = r & 15;
  const int f = dflag[0];
  const float A = -expf(load1(A_log, d * NST + n, f));
  const float dpar = load1(Dp, d, f);
  float h = Hin[gid];
  const int t0 = c * CLEN;
  for (int tt = 0; tt < CLEN; tt++) {
    int t = t0 + tt;
    float dl = bf2f(delta[(size_t)t * DKV + d]);
    float uu = bf2f(u[(size_t)t * DKV + d]);
    float bm = xd[(size_t)t * 96 + DTR + n];
    float cm = xd[(size_t)t * 96 + DTR + NST + n];
    float a = expf(dl * A);
    h = a * h + dl * bm * uu;
    float part = h * cm;
    part += __shfl_xor(part, 1);
    part += __shfl_xor(part, 2);
    part += __shfl_xor(part, 4);
    part += __shfl_xor(part, 8);
    if (n == 0) u[(size_t)t * DKV + d] = __float2bfloat16(part + dpar * uu);
  }
}

// ---------------------------------------------------------------------------
// Sliding-window attention. Block = (qtile of 64, head). 32-key LDS chunks,
// online softmax. S-phase: thread (qg=tid/16 -> 4 rows, kg=tid&15 -> 2 keys).
// PV-phase: same rows, cols kg*8..+7. m/l/alpha stay in registers (same rows).
// kv: bf16 [T][1024], k at cols [0,512), v at [512,1024).
// ---------------------------------------------------------------------------
__global__ __launch_bounds__(256) void attn_kernel(
    const bf16* __restrict__ q, const bf16* __restrict__ kv, bf16* __restrict__ y)
{
  __shared__ float qs[64][132];
  __shared__ float ks[32][132];
  __shared__ float vs[32][132];
  __shared__ float ps[64][33];
  const int tid = threadIdx.x;
  const int qt = blockIdx.x;      // 0..63
  const int h = blockIdx.y;       // 0..15
  const int kvh = h >> 2;
  const int t0 = qt * 64;
  const float scale = 0.088388347648318447f;  // 1/sqrt(128)

  for (int e = tid; e < 64 * 16; e += 256) {
    int row = e >> 4, c8 = (e & 15) * 8;
    F8 v = load_b8(q + (size_t)(t0 + row) * QDIM + h * DH + c8);
#pragma unroll
    for (int j = 0; j < 8; j++) qs[row][c8 + j] = v.v[j] * scale;
  }

  const int qg = tid >> 4;   // rows qg*4..+3
  const int kg = tid & 15;

  float m[4], l[4], O[4][8];
#pragma unroll
  for (int i = 0; i < 4; i++) {
    m[i] = -1e30f; l[i] = 0.f;
#pragma unroll
    for (int j = 0; j < 8; j++) O[i][j] = 0.f;
  }

  const int kb_start = (t0 > WIN - 1) ? ((t0 - (WIN - 1)) >> 5) : 0;
  const int kb_end = (t0 + 63) >> 5;

  for (int kb = kb_start; kb <= kb_end; kb++) {
    __syncthreads();  // protect ks/vs/qs from previous readers
    for (int e = tid; e < 32 * 16; e += 256) {
      int row = e >> 4, c8 = (e & 15) * 8;
      int kt = kb * 32 + row;
      F8 kf = load_b8(kv + (size_t)kt * DKV + kvh * DH + c8);
      F8 vf = load_b8(kv + (size_t)kt * DKV + KDIM + kvh * DH + c8);
#pragma unroll
      for (int j = 0; j < 8; j++) { ks[row][c8 + j] = kf.v[j]; vs[row][c8 + j] = vf.v[j]; }
    }
    __syncthreads();

    float S[4][2] = {};
    const int krow0 = kg * 2;
    for (int c = 0; c < DH; c += 4) {
      float4 b0 = *(const float4*)&ks[krow0][c];
      float4 b1 = *(const float4*)&ks[krow0 + 1][c];
#pragma unroll
      for (int i = 0; i < 4; i++) {
        float4 a = *(const float4*)&qs[qg * 4 + i][c];
        S[i][0] = fmaf(a.x, b0.x, fmaf(a.y, b0.y, fmaf(a.z, b0.z, fmaf(a.w, b0.w, S[i][0]))));
        S[i][1] = fmaf(a.x, b1.x, fmaf(a.y, b1.y, fmaf(a.z, b1.z, fmaf(a.w, b1.w, S[i][1]))));
      }
    }

    float alpha[4];
#pragma unroll
    for (int i = 0; i < 4; i++) {
      int qa = t0 + qg * 4 + i;
      int ka0 = kb * 32 + krow0, ka1 = ka0 + 1;
      bool vld0 = (ka0 <= qa) && (ka0 >= qa - (WIN - 1));
      bool vld1 = (ka1 <= qa) && (ka1 >= qa - (WIN - 1));
      float s0 = vld0 ? S[i][0] : -1e30f;
      float s1 = vld1 ? S[i][1] : -1e30f;
      float rm = fmaxf(s0, s1);
      rm = fmaxf(rm, __shfl_xor(rm, 1));
      rm = fmaxf(rm, __shfl_xor(rm, 2));
      rm = fmaxf(rm, __shfl_xor(rm, 4));
      rm = fmaxf(rm, __shfl_xor(rm, 8));
      float mnew = fmaxf(m[i], rm);
      alpha[i] = expf(m[i] - mnew);  // (-1e30)-(-1e30)=0 -> alpha=1, harmless
      float p0 = vld0 ? expf(s0 - mnew) : 0.f;
      float p1 = vld1 ? expf(s1 - mnew) : 0.f;
      float rs = p0 + p1;
      rs += __shfl_xor(rs, 1);
      rs += __shfl_xor(rs, 2);
      rs += __shfl_xor(rs, 4);
      rs += __shfl_xor(rs, 8);
      l[i] = l[i] * alpha[i] + rs;
      m[i] = mnew;
      ps[qg * 4 + i][krow0] = p0;
      ps[qg * 4 + i][krow0 + 1] = p1;
    }
    __syncthreads();

#pragma unroll
    for (int i = 0; i < 4; i++)
#pragma unroll
      for (int j = 0; j < 8; j++) O[i][j] *= alpha[i];
    for (int k = 0; k < 32; k++) {
      float4 v0 = *(const float4*)&vs[k][kg * 8];
      float4 v1 = *(const float4*)&vs[k][kg * 8 + 4];
      float vv[8] = {v0.x, v0.y, v0.z, v0.w, v1.x, v1.y, v1.z, v1.w};
#pragma unroll
      for (int i = 0; i < 4; i++) {
        float p = ps[qg * 4 + i][k];
#pragma unroll
        for (int j = 0; j < 8; j++) O[i][j] = fmaf(p, vv[j], O[i][j]);
      }
    }
  }

#pragma unroll
  for (int i = 0; i < 4; i++) {
    float inv = 1.f / l[i];
    int row = t0 + qg * 4 + i;
    ushort4 p0 = pack4(O[i][0] * inv, O[i][1] * inv, O[i][2] * inv, O[i][3] * inv);
    ushort4 p1 = pack4(O[i][4] * inv, O[i][5] * inv, O[i][6] * inv, O[i][7] * inv);
    *reinterpret_cast<ushort4*>(y + (size_t)row * QDIM + h * DH + kg * 8) = p0;
    *reinterpret_cast<ushort4*>(y + (size_t)row * QDIM + h * DH + kg * 8 + 4) = p1;
  }
}

// ---------------------------------------------------------------------------
extern "C" void kernel_launch(void* const* d_in, const int* in_sizes, int n_in,
                              void* d_out, int out_size, void* d_ws, size_t ws_size,
                              hipStream_t stream)
{
  const void* x      = d_in[0];
  const void* W_attn = d_in[1];
  const void* A_log  = d_in[2];
  const void* xpw    = d_in[3];
  const void* dtw    = d_in[4];
  const void* dtb    = d_in[5];
  const void* Dp     = d_in[6];
  const void* W_o    = d_in[7];
  // d_in[8] = window_size = 512 (compile-time WIN)

  // Workspace layout, TOTAL ~25.5 MiB:
  char* ws = (char*)d_ws;
  int*   dflag = (int*)ws;   ws += 256;
  bf16*  u     = (bf16*)ws;  ws += (size_t)T_SEQ * DKV * 2;       // 8.4 MB, becomes kvs in-place
  float* xd    = (float*)ws; ws += (size_t)T_SEQ * 96 * 4;        // 1.6 MB
  char*  yreg  = ws;                                               // y aliases delta+Pb+Hl (16.8 MB)
  bf16*  delta = (bf16*)ws;  ws += (size_t)T_SEQ * DKV * 2;       // 8.4 MB
  float* Pb    = (float*)ws; ws += (size_t)NCHUNK * DKV * NST * 4; // 4.2 MB (becomes Hin in-place)
  float* Hl    = (float*)ws; ws += (size_t)NCHUNK * DKV * NST * 4; // 4.2 MB
  bf16*  y     = (bf16*)yreg;

  bf16*  q_bf = (bf16*)d_out;   // q (16.8 MB bf16) parks in d_out (33.5 MB fp32)
  float* out  = (float*)d_out;  // final gemm overwrites all of d_out with fp32

  detect_dtype<<<1, 64, 0, stream>>>((const unsigned short*)x, dflag);
  gemm_bt<<<dim3(QKVD / 128, T_SEQ / 128), 256, 0, stream>>>(
      x, W_attn, dflag, 2, 2, T_SEQ, QKVD, NEMBD, 0, q_bf, u, nullptr);
  xdbl_kernel<<<T_SEQ, 128, 0, stream>>>(u, xpw, dflag, xd);
  delta_kernel<<<T_SEQ, 256, 0, stream>>>(xd, dtw, dtb, dflag, delta);
  scan_pass1<<<4096, 256, 0, stream>>>(delta, u, xd, A_log, dflag, Pb, Hl);
  scan_combine<<<64, 256, 0, stream>>>(Pb, Hl);
  scan_pass2<<<4096, 256, 0, stream>>>(delta, u, xd, A_log, Dp, dflag, Pb);
  attn_kernel<<<dim3(T_SEQ / 64, NH), 256, 0, stream>>>(q_bf, u, y);
  gemm_bt<<<dim3(QDIM / 128, T_SEQ / 128), 256, 0, stream>>>(
      y, W_o, dflag, 0, 2, T_SEQ, QDIM, QDIM, 1, nullptr, nullptr, out);
}

// Round 5
// 1041.052 us; speedup vs baseline: 1.8317x; 1.8317x over previous
//
#include <hip/hip_runtime.h>
#include <hip/hip_bf16.h>

typedef __hip_bfloat16 bf16;
typedef __attribute__((ext_vector_type(8))) short bf16x8;   // 8 bf16 = 4 VGPRs
typedef __attribute__((ext_vector_type(4))) float f32x4;

#define T_SEQ 4096
#define NEMBD 2048
#define QKVD  3072
#define QDIM  2048
#define DKV   1024
#define KDIM  512
#define NH    16
#define DH    128
#define NST   16
#define DTR   64
#define WIN   512
#define NCHUNK 64
#define CLEN   64

__device__ inline float bf2f(bf16 x) { return __bfloat162float(x); }

struct F8 { float v[8]; };

// load 8 contiguous bf16 (16B) and widen to fp32 (bf16 bits << 16)
__device__ inline F8 load_b8(const bf16* p) {
  union { uint4 q; unsigned short s[8]; } u;
  u.q = *reinterpret_cast<const uint4*>(p);
  F8 r;
#pragma unroll
  for (int i = 0; i < 8; i++) r.v[i] = __uint_as_float((unsigned)u.s[i] << 16);
  return r;
}

// load 8 elements [idx, idx+8) from an INPUT array whose real dtype is
// bf16 (f32flag=0) or fp32 (f32flag=1). idx must be a multiple of 4.
__device__ inline F8 load8(const void* base, size_t idx, int f32flag) {
  if (f32flag) {
    const float4* p = reinterpret_cast<const float4*>((const float*)base + idx);
    float4 a = p[0], b = p[1];
    F8 r;
    r.v[0]=a.x; r.v[1]=a.y; r.v[2]=a.z; r.v[3]=a.w;
    r.v[4]=b.x; r.v[5]=b.y; r.v[6]=b.z; r.v[7]=b.w;
    return r;
  }
  return load_b8((const bf16*)base + idx);
}

__device__ inline float load1(const void* base, size_t idx, int f32flag) {
  return f32flag ? ((const float*)base)[idx] : bf2f(((const bf16*)base)[idx]);
}

__device__ inline unsigned short f2b_bits(float f) {
  bf16 h = __float2bfloat16(f);  // RNE
  union { bf16 h; unsigned short u; } c; c.h = h; return c.u;
}

__device__ inline ushort4 pack4(float a, float b, float c, float d) {
  ushort4 r; r.x = f2b_bits(a); r.y = f2b_bits(b); r.z = f2b_bits(c); r.w = f2b_bits(d);
  return r;
}

// async global->LDS, 16B per lane; LDS dest is wave-uniform base + lane*16.
__device__ inline void gld_lds16(const void* g, void* l) {
  __builtin_amdgcn_global_load_lds(
      (const __attribute__((address_space(1))) unsigned int*)g,
      (__attribute__((address_space(3))) unsigned int*)l, 16, 0, 0);
}

// ---------------------------------------------------------------------------
// Input-dtype detection (round-1/2 evidence: fp32; keep the hedge, zero cost).
// ---------------------------------------------------------------------------
__global__ void detect_dtype(const unsigned short* __restrict__ x, int* __restrict__ flag) {
  if (threadIdx.x == 0 && blockIdx.x == 0) {
    int c = 0;
    for (int i = 0; i < 128; i++) {
      float v = __uint_as_float((unsigned)x[i] << 16);
      float a = fabsf(v);
      if (a >= 1e-8f && a <= 1e4f) c++;
    }
    flag[0] = (c >= 120) ? 0 : 1;
  }
}

// convert n8*8 elements (fp32 or bf16 per dflag) -> packed bf16 bits
__global__ __launch_bounds__(256) void cvt_bf16(
    const void* __restrict__ in, const int* __restrict__ dflag,
    unsigned short* __restrict__ out, int n8)
{
  int i = blockIdx.x * 256 + threadIdx.x;
  if (i >= n8) return;
  const int f = dflag[0];
  F8 v = load8(in, (size_t)i * 8, f);
  ushort4* o = (ushort4*)(out + (size_t)i * 8);
  o[0] = pack4(v.v[0], v.v[1], v.v[2], v.v[3]);
  o[1] = pack4(v.v[4], v.v[5], v.v[6], v.v[7]);
}

// ---------------------------------------------------------------------------
// MFMA GEMM: C[M,N] = A[M,K] * B[N,K]^T, A/B bf16-bits row-major.
// 128x128 tile, BK=32, 256 threads = 4 waves, each wave 64x64 via 4x4
// mfma_f32_16x16x32_bf16 tiles. global_load_lds width-16 staging (m97).
// mode 0: cols <2048 -> oq bf16 [M,2048]; cols >=2048 -> ou bf16 [M,1024]
// mode 1: fp32 out oc [M,N]
// ---------------------------------------------------------------------------
__global__ __launch_bounds__(256) void gemm_mfma(
    const unsigned short* __restrict__ A, const unsigned short* __restrict__ B,
    int M, int N, int K, int mode,
    bf16* __restrict__ oq, bf16* __restrict__ ou, float* __restrict__ oc)
{
  __shared__ unsigned short As[128 * 32];   // [row][32] contiguous, no padding
  __shared__ unsigned short Bs[128 * 32];
  const int tid = threadIdx.x;
  const int wave = tid >> 6, lane = tid & 63;
  const int quad = lane >> 4, l16 = lane & 15;
  const int bm = blockIdx.y * 128, bn = blockIdx.x * 128;
  const int wm = (wave >> 1) * 64, wn = (wave & 1) * 64;

  // staging: wave stages rows [wave*32, wave*32+32) of both tiles,
  // 2 segments of 16 rows; lane -> row srow+lane/4, col (lane&3)*8
  const int srow = wave * 32;
  const int lrow = lane >> 2;
  const int lcol = (lane & 3) * 8;

  f32x4 acc[4][4];
#pragma unroll
  for (int i = 0; i < 4; i++)
#pragma unroll
    for (int j = 0; j < 4; j++) acc[i][j] = f32x4{0.f, 0.f, 0.f, 0.f};

  const unsigned short* Ab = A + (size_t)bm * K;
  const unsigned short* Bb = B + (size_t)bn * K;

  for (int k0 = 0; k0 < K; k0 += 32) {
    __syncthreads();  // previous iter's ds_reads done before overwrite
    gld_lds16(Ab + (size_t)(srow + lrow) * K + k0 + lcol,      &As[srow * 32]);
    gld_lds16(Ab + (size_t)(srow + 16 + lrow) * K + k0 + lcol, &As[(srow + 16) * 32]);
    gld_lds16(Bb + (size_t)(srow + lrow) * K + k0 + lcol,      &Bs[srow * 32]);
    gld_lds16(Bb + (size_t)(srow + 16 + lrow) * K + k0 + lcol, &Bs[(srow + 16) * 32]);
    __syncthreads();  // compiler drains vmcnt before s_barrier

    bf16x8 af[4], bfr[4];
#pragma unroll
    for (int i = 0; i < 4; i++)
      af[i] = *(const bf16x8*)&As[(wm + i * 16 + l16) * 32 + quad * 8];
#pragma unroll
    for (int j = 0; j < 4; j++)
      bfr[j] = *(const bf16x8*)&Bs[(wn + j * 16 + l16) * 32 + quad * 8];
#pragma unroll
    for (int i = 0; i < 4; i++)
#pragma unroll
      for (int j = 0; j < 4; j++)
        acc[i][j] = __builtin_amdgcn_mfma_f32_16x16x32_bf16(af[i], bfr[j], acc[i][j], 0, 0, 0);
  }

  // C/D layout: col = lane&15, row = quad*4 + reg   [verified m89/m91]
#pragma unroll
  for (int i = 0; i < 4; i++)
#pragma unroll
    for (int j = 0; j < 4; j++) {
      int gm0 = bm + wm + i * 16 + quad * 4;
      int gn  = bn + wn + j * 16 + l16;
#pragma unroll
      for (int r = 0; r < 4; r++) {
        int gm = gm0 + r;
        float v = acc[i][j][r];
        if (mode == 0) {
          if (gn < QDIM) oq[(size_t)gm * QDIM + gn] = __float2bfloat16(v);
          else           ou[(size_t)gm * DKV + (gn - QDIM)] = __float2bfloat16(v);
        } else {
          oc[(size_t)gm * N + gn] = v;
        }
      }
    }
}

// ---------------------------------------------------------------------------
// x_dbl[t,e] = dot(u[t,:1024], x_proj_w[e,:1024]),  e in [0,96)
// ---------------------------------------------------------------------------
__global__ __launch_bounds__(128) void xdbl_kernel(
    const bf16* __restrict__ u, const void* __restrict__ xpw,
    const int* __restrict__ dflag, float* __restrict__ xd)
{
  __shared__ float us[DKV];
  const int t = blockIdx.x, tid = threadIdx.x;
  const int f = dflag[0];
  const bf16* ur = u + (size_t)t * DKV;
  for (int i = tid; i < DKV; i += 128) us[i] = bf2f(ur[i]);
  __syncthreads();
  if (tid < 96) {
    float acc = 0.f;
    const size_t wb = (size_t)tid * DKV;
    for (int k = 0; k < DKV; k += 8) {
      F8 w = load8(xpw, wb + k, f);
#pragma unroll
      for (int j = 0; j < 8; j++) acc = fmaf(w.v[j], us[k + j], acc);
    }
    xd[(size_t)t * 96 + tid] = acc;
  }
}

// ---------------------------------------------------------------------------
// delta[t,d] = softplus(dot(x_dbl[t,0:64], dt_proj_w[d,:]) + dt_proj_b[d])
// ---------------------------------------------------------------------------
__global__ __launch_bounds__(256) void delta_kernel(
    const float* __restrict__ xd, const void* __restrict__ dtw,
    const void* __restrict__ dtb, const int* __restrict__ dflag,
    bf16* __restrict__ delta)
{
  __shared__ float dts[DTR];
  const int t = blockIdx.x, tid = threadIdx.x;
  const int f = dflag[0];
  if (tid < DTR) dts[tid] = xd[(size_t)t * 96 + tid];
  __syncthreads();
  for (int d = tid; d < DKV; d += 256) {
    float acc = load1(dtb, d, f);
    const size_t wb = (size_t)d * DTR;
#pragma unroll
    for (int k = 0; k < DTR; k += 8) {
      F8 w = load8(dtw, wb + k, f);
#pragma unroll
      for (int j = 0; j < 8; j++) acc = fmaf(w.v[j], dts[k + j], acc);
    }
    float sp = fmaxf(acc, 0.f) + log1pf(expf(-fabsf(acc)));  // stable softplus
    delta[(size_t)t * DKV + d] = __float2bfloat16(sp);
  }
}

// ---------------------------------------------------------------------------
// Scan pass1: per (chunk c, d, n): P = prod(a_t), Hl = local scan from h=0
// ---------------------------------------------------------------------------
__global__ __launch_bounds__(256) void scan_pass1(
    const bf16* __restrict__ delta, const bf16* __restrict__ u,
    const float* __restrict__ xd, const void* __restrict__ A_log,
    const int* __restrict__ dflag, float* __restrict__ Pb, float* __restrict__ Hl)
{
  const int gid = blockIdx.x * 256 + threadIdx.x;
  const int c = gid >> 14;
  const int r = gid & 16383;
  const int d = r >> 4, n = r & 15;
  const int f = dflag[0];
  const float A = -expf(load1(A_log, d * NST + n, f));
  float p = 1.f, h = 0.f;
  const int t0 = c * CLEN;
  for (int tt = 0; tt < CLEN; tt++) {
    int t = t0 + tt;
    float dl = bf2f(delta[(size_t)t * DKV + d]);
    float uu = bf2f(u[(size_t)t * DKV + d]);
    float bm = xd[(size_t)t * 96 + DTR + n];
    float a = expf(dl * A);
    h = a * h + dl * bm * uu;
    p *= a;
  }
  Pb[gid] = p;
  Hl[gid] = h;
}

// in-place: Pb becomes Hin (chunk-entry state)
__global__ __launch_bounds__(256) void scan_combine(
    float* __restrict__ Pb, const float* __restrict__ Hl)
{
  const int idx = blockIdx.x * 256 + threadIdx.x;  // 0..16383
  float run = 0.f;
  for (int c = 0; c < NCHUNK; c++) {
    size_t off = (size_t)c * 16384 + idx;
    float p = Pb[off], hl = Hl[off];
    Pb[off] = run;
    run = p * run + hl;
  }
}

// pass2: recompute with correct h_init, reduce y over n (16 lanes), add D*u.
// kv written IN-PLACE over u (same 16-lane group, same iteration).
__global__ __launch_bounds__(256) void scan_pass2(
    const bf16* __restrict__ delta, bf16* __restrict__ u,
    const float* __restrict__ xd, const void* __restrict__ A_log,
    const void* __restrict__ Dp, const int* __restrict__ dflag,
    const float* __restrict__ Hin)
{
  const int gid = blockIdx.x * 256 + threadIdx.x;
  const int c = gid >> 14;
  const int r = gid & 16383;
  const int d = r >> 4, n = r & 15;
  const int f = dflag[0];
  const float A = -expf(load1(A_log, d * NST + n, f));
  const float dpar = load1(Dp, d, f);
  float h = Hin[gid];
  const int t0 = c * CLEN;
  for (int tt = 0; tt < CLEN; tt++) {
    int t = t0 + tt;
    float dl = bf2f(delta[(size_t)t * DKV + d]);
    float uu = bf2f(u[(size_t)t * DKV + d]);
    float bm = xd[(size_t)t * 96 + DTR + n];
    float cm = xd[(size_t)t * 96 + DTR + NST + n];
    float a = expf(dl * A);
    h = a * h + dl * bm * uu;
    float part = h * cm;
    part += __shfl_xor(part, 1);
    part += __shfl_xor(part, 2);
    part += __shfl_xor(part, 4);
    part += __shfl_xor(part, 8);
    if (n == 0) u[(size_t)t * DKV + d] = __float2bfloat16(part + dpar * uu);
  }
}

// ---------------------------------------------------------------------------
// Sliding-window attention (unchanged from round 4 — verified correct).
// ---------------------------------------------------------------------------
__global__ __launch_bounds__(256) void attn_kernel(
    const bf16* __restrict__ q, const bf16* __restrict__ kv, bf16* __restrict__ y)
{
  __shared__ float qs[64][132];
  __shared__ float ks[32][132];
  __shared__ float vs[32][132];
  __shared__ float ps[64][33];
  const int tid = threadIdx.x;
  const int qt = blockIdx.x;
  const int h = blockIdx.y;
  const int kvh = h >> 2;
  const int t0 = qt * 64;
  const float scale = 0.088388347648318447f;

  for (int e = tid; e < 64 * 16; e += 256) {
    int row = e >> 4, c8 = (e & 15) * 8;
    F8 v = load_b8(q + (size_t)(t0 + row) * QDIM + h * DH + c8);
#pragma unroll
    for (int j = 0; j < 8; j++) qs[row][c8 + j] = v.v[j] * scale;
  }

  const int qg = tid >> 4;
  const int kg = tid & 15;

  float m[4], l[4], O[4][8];
#pragma unroll
  for (int i = 0; i < 4; i++) {
    m[i] = -1e30f; l[i] = 0.f;
#pragma unroll
    for (int j = 0; j < 8; j++) O[i][j] = 0.f;
  }

  const int kb_start = (t0 > WIN - 1) ? ((t0 - (WIN - 1)) >> 5) : 0;
  const int kb_end = (t0 + 63) >> 5;

  for (int kb = kb_start; kb <= kb_end; kb++) {
    __syncthreads();
    for (int e = tid; e < 32 * 16; e += 256) {
      int row = e >> 4, c8 = (e & 15) * 8;
      int kt = kb * 32 + row;
      F8 kf = load_b8(kv + (size_t)kt * DKV + kvh * DH + c8);
      F8 vf = load_b8(kv + (size_t)kt * DKV + KDIM + kvh * DH + c8);
#pragma unroll
      for (int j = 0; j < 8; j++) { ks[row][c8 + j] = kf.v[j]; vs[row][c8 + j] = vf.v[j]; }
    }
    __syncthreads();

    float S[4][2] = {};
    const int krow0 = kg * 2;
    for (int c = 0; c < DH; c += 4) {
      float4 b0 = *(const float4*)&ks[krow0][c];
      float4 b1 = *(const float4*)&ks[krow0 + 1][c];
#pragma unroll
      for (int i = 0; i < 4; i++) {
        float4 a = *(const float4*)&qs[qg * 4 + i][c];
        S[i][0] = fmaf(a.x, b0.x, fmaf(a.y, b0.y, fmaf(a.z, b0.z, fmaf(a.w, b0.w, S[i][0]))));
        S[i][1] = fmaf(a.x, b1.x, fmaf(a.y, b1.y, fmaf(a.z, b1.z, fmaf(a.w, b1.w, S[i][1]))));
      }
    }

    float alpha[4];
#pragma unroll
    for (int i = 0; i < 4; i++) {
      int qa = t0 + qg * 4 + i;
      int ka0 = kb * 32 + krow0, ka1 = ka0 + 1;
      bool vld0 = (ka0 <= qa) && (ka0 >= qa - (WIN - 1));
      bool vld1 = (ka1 <= qa) && (ka1 >= qa - (WIN - 1));
      float s0 = vld0 ? S[i][0] : -1e30f;
      float s1 = vld1 ? S[i][1] : -1e30f;
      float rm = fmaxf(s0, s1);
      rm = fmaxf(rm, __shfl_xor(rm, 1));
      rm = fmaxf(rm, __shfl_xor(rm, 2));
      rm = fmaxf(rm, __shfl_xor(rm, 4));
      rm = fmaxf(rm, __shfl_xor(rm, 8));
      float mnew = fmaxf(m[i], rm);
      alpha[i] = expf(m[i] - mnew);
      float p0 = vld0 ? expf(s0 - mnew) : 0.f;
      float p1 = vld1 ? expf(s1 - mnew) : 0.f;
      float rs = p0 + p1;
      rs += __shfl_xor(rs, 1);
      rs += __shfl_xor(rs, 2);
      rs += __shfl_xor(rs, 4);
      rs += __shfl_xor(rs, 8);
      l[i] = l[i] * alpha[i] + rs;
      m[i] = mnew;
      ps[qg * 4 + i][krow0] = p0;
      ps[qg * 4 + i][krow0 + 1] = p1;
    }
    __syncthreads();

#pragma unroll
    for (int i = 0; i < 4; i++)
#pragma unroll
      for (int j = 0; j < 8; j++) O[i][j] *= alpha[i];
    for (int k = 0; k < 32; k++) {
      float4 v0 = *(const float4*)&vs[k][kg * 8];
      float4 v1 = *(const float4*)&vs[k][kg * 8 + 4];
      float vv[8] = {v0.x, v0.y, v0.z, v0.w, v1.x, v1.y, v1.z, v1.w};
#pragma unroll
      for (int i = 0; i < 4; i++) {
        float p = ps[qg * 4 + i][k];
#pragma unroll
        for (int j = 0; j < 8; j++) O[i][j] = fmaf(p, vv[j], O[i][j]);
      }
    }
  }

#pragma unroll
  for (int i = 0; i < 4; i++) {
    float inv = 1.f / l[i];
    int row = t0 + qg * 4 + i;
    ushort4 p0 = pack4(O[i][0] * inv, O[i][1] * inv, O[i][2] * inv, O[i][3] * inv);
    ushort4 p1 = pack4(O[i][4] * inv, O[i][5] * inv, O[i][6] * inv, O[i][7] * inv);
    *reinterpret_cast<ushort4*>(y + (size_t)row * QDIM + h * DH + kg * 8) = p0;
    *reinterpret_cast<ushort4*>(y + (size_t)row * QDIM + h * DH + kg * 8 + 4) = p1;
  }
}

// ---------------------------------------------------------------------------
extern "C" void kernel_launch(void* const* d_in, const int* in_sizes, int n_in,
                              void* d_out, int out_size, void* d_ws, size_t ws_size,
                              hipStream_t stream)
{
  const void* x      = d_in[0];
  const void* W_attn = d_in[1];
  const void* A_log  = d_in[2];
  const void* xpw    = d_in[3];
  const void* dtw    = d_in[4];
  const void* dtb    = d_in[5];
  const void* Dp     = d_in[6];
  const void* W_o    = d_in[7];

  // Workspace, TOTAL ~64 MiB (round-2/3 evidence: 98 MB was valid):
  char* ws = (char*)d_ws;
  int*   dflag = (int*)ws;   ws += 256;
  bf16*  u     = (bf16*)ws;  ws += (size_t)T_SEQ * DKV * 2;        // 8.4 MB, becomes kv in-place
  float* xd    = (float*)ws; ws += (size_t)T_SEQ * 96 * 4;         // 1.6 MB
  char*  yreg  = ws;                                                // y aliases delta+Pb+Hl (16.78 MB)
  bf16*  delta = (bf16*)ws;  ws += (size_t)T_SEQ * DKV * 2;        // 8.4 MB
  float* Pb    = (float*)ws; ws += (size_t)NCHUNK * DKV * NST * 4; // 4.2 MB (becomes Hin)
  float* Hl    = (float*)ws; ws += (size_t)NCHUNK * DKV * NST * 4; // 4.2 MB
  unsigned short* x_bf  = (unsigned short*)ws; ws += (size_t)T_SEQ * NEMBD * 2;  // 16.8 MB
  unsigned short* wa_bf = (unsigned short*)ws; ws += (size_t)QKVD * NEMBD * 2;   // 12.6 MB
  unsigned short* wo_bf = (unsigned short*)ws; ws += (size_t)NEMBD * QDIM * 2;   //  8.4 MB
  bf16*  y     = (bf16*)yreg;

  bf16*  q_bf = (bf16*)d_out;   // q parks in d_out until gemm2 overwrites it
  float* out  = (float*)d_out;

  detect_dtype<<<1, 64, 0, stream>>>((const unsigned short*)x, dflag);
  cvt_bf16<<<(T_SEQ * NEMBD / 8 + 255) / 256, 256, 0, stream>>>(x, dflag, x_bf, T_SEQ * NEMBD / 8);
  cvt_bf16<<<(QKVD * NEMBD / 8 + 255) / 256, 256, 0, stream>>>(W_attn, dflag, wa_bf, QKVD * NEMBD / 8);
  cvt_bf16<<<(NEMBD * QDIM / 8 + 255) / 256, 256, 0, stream>>>(W_o, dflag, wo_bf, NEMBD * QDIM / 8);

  gemm_mfma<<<dim3(QKVD / 128, T_SEQ / 128), 256, 0, stream>>>(
      x_bf, wa_bf, T_SEQ, QKVD, NEMBD, 0, q_bf, u, nullptr);
  xdbl_kernel<<<T_SEQ, 128, 0, stream>>>(u, xpw, dflag, xd);
  delta_kernel<<<T_SEQ, 256, 0, stream>>>(xd, dtw, dtb, dflag, delta);
  scan_pass1<<<4096, 256, 0, stream>>>(delta, u, xd, A_log, dflag, Pb, Hl);
  scan_combine<<<64, 256, 0, stream>>>(Pb, Hl);
  scan_pass2<<<4096, 256, 0, stream>>>(delta, u, xd, A_log, Dp, dflag, Pb);
  attn_kernel<<<dim3(T_SEQ / 64, NH), 256, 0, stream>>>(q_bf, u, y);
  gemm_mfma<<<dim3(QDIM / 128, T_SEQ / 128), 256, 0, stream>>>(
      (const unsigned short*)y, wo_bf, T_SEQ, QDIM, QDIM, 1, nullptr, nullptr, out);
}

// Round 6
// 793.719 us; speedup vs baseline: 2.4024x; 1.3116x over previous
//
#include <hip/hip_runtime.h>
#include <hip/hip_bf16.h>

typedef __hip_bfloat16 bf16;
typedef __attribute__((ext_vector_type(8))) short bf16x8;   // 8 bf16 = 4 VGPRs
typedef __attribute__((ext_vector_type(4))) float f32x4;

#define T_SEQ 4096
#define NEMBD 2048
#define QKVD  3072
#define QDIM  2048
#define DKV   1024
#define KDIM  512
#define NH    16
#define DH    128
#define NST   16
#define DTR   64
#define WIN   512
#define NCHUNK 64
#define CLEN   64

__device__ inline float bf2f(bf16 x) { return __bfloat162float(x); }

struct F8 { float v[8]; };

// load 8 contiguous bf16 (16B) and widen to fp32 (bf16 bits << 16)
__device__ inline F8 load_b8(const bf16* p) {
  union { uint4 q; unsigned short s[8]; } u;
  u.q = *reinterpret_cast<const uint4*>(p);
  F8 r;
#pragma unroll
  for (int i = 0; i < 8; i++) r.v[i] = __uint_as_float((unsigned)u.s[i] << 16);
  return r;
}

// load 8 elements [idx, idx+8) from an INPUT array whose real dtype is
// bf16 (f32flag=0) or fp32 (f32flag=1). idx must be a multiple of 4.
__device__ inline F8 load8(const void* base, size_t idx, int f32flag) {
  if (f32flag) {
    const float4* p = reinterpret_cast<const float4*>((const float*)base + idx);
    float4 a = p[0], b = p[1];
    F8 r;
    r.v[0]=a.x; r.v[1]=a.y; r.v[2]=a.z; r.v[3]=a.w;
    r.v[4]=b.x; r.v[5]=b.y; r.v[6]=b.z; r.v[7]=b.w;
    return r;
  }
  return load_b8((const bf16*)base + idx);
}

__device__ inline float load1(const void* base, size_t idx, int f32flag) {
  return f32flag ? ((const float*)base)[idx] : bf2f(((const bf16*)base)[idx]);
}

__device__ inline unsigned short f2b_bits(float f) {
  bf16 h = __float2bfloat16(f);  // RNE
  union { bf16 h; unsigned short u; } c; c.h = h; return c.u;
}

__device__ inline ushort4 pack4(float a, float b, float c, float d) {
  ushort4 r; r.x = f2b_bits(a); r.y = f2b_bits(b); r.z = f2b_bits(c); r.w = f2b_bits(d);
  return r;
}

// async global->LDS, 16B per lane; LDS dest is wave-uniform base + lane*16.
__device__ inline void gld_lds16(const void* g, void* l) {
  __builtin_amdgcn_global_load_lds(
      (const __attribute__((address_space(1))) unsigned int*)g,
      (__attribute__((address_space(3))) unsigned int*)l, 16, 0, 0);
}

// ---------------------------------------------------------------------------
// Input-dtype detection (round-1/2 evidence: fp32; keep the hedge, zero cost).
// ---------------------------------------------------------------------------
__global__ void detect_dtype(const unsigned short* __restrict__ x, int* __restrict__ flag) {
  if (threadIdx.x == 0 && blockIdx.x == 0) {
    int c = 0;
    for (int i = 0; i < 128; i++) {
      float v = __uint_as_float((unsigned)x[i] << 16);
      float a = fabsf(v);
      if (a >= 1e-8f && a <= 1e4f) c++;
    }
    flag[0] = (c >= 120) ? 0 : 1;
  }
}

// convert n8*8 elements (fp32 or bf16 per dflag) -> packed bf16 bits
__global__ __launch_bounds__(256) void cvt_bf16(
    const void* __restrict__ in, const int* __restrict__ dflag,
    unsigned short* __restrict__ out, int n8)
{
  int i = blockIdx.x * 256 + threadIdx.x;
  if (i >= n8) return;
  const int f = dflag[0];
  F8 v = load8(in, (size_t)i * 8, f);
  ushort4* o = (ushort4*)(out + (size_t)i * 8);
  o[0] = pack4(v.v[0], v.v[1], v.v[2], v.v[3]);
  o[1] = pack4(v.v[4], v.v[5], v.v[6], v.v[7]);
}

// ---------------------------------------------------------------------------
// MFMA GEMM (unchanged from round 5 — verified, 0.078 absmax).
// ---------------------------------------------------------------------------
__global__ __launch_bounds__(256) void gemm_mfma(
    const unsigned short* __restrict__ A, const unsigned short* __restrict__ B,
    int M, int N, int K, int mode,
    bf16* __restrict__ oq, bf16* __restrict__ ou, float* __restrict__ oc)
{
  __shared__ unsigned short As[128 * 32];
  __shared__ unsigned short Bs[128 * 32];
  const int tid = threadIdx.x;
  const int wave = tid >> 6, lane = tid & 63;
  const int quad = lane >> 4, l16 = lane & 15;
  const int bm = blockIdx.y * 128, bn = blockIdx.x * 128;
  const int wm = (wave >> 1) * 64, wn = (wave & 1) * 64;

  const int srow = wave * 32;
  const int lrow = lane >> 2;
  const int lcol = (lane & 3) * 8;

  f32x4 acc[4][4];
#pragma unroll
  for (int i = 0; i < 4; i++)
#pragma unroll
    for (int j = 0; j < 4; j++) acc[i][j] = f32x4{0.f, 0.f, 0.f, 0.f};

  const unsigned short* Ab = A + (size_t)bm * K;
  const unsigned short* Bb = B + (size_t)bn * K;

  for (int k0 = 0; k0 < K; k0 += 32) {
    __syncthreads();
    gld_lds16(Ab + (size_t)(srow + lrow) * K + k0 + lcol,      &As[srow * 32]);
    gld_lds16(Ab + (size_t)(srow + 16 + lrow) * K + k0 + lcol, &As[(srow + 16) * 32]);
    gld_lds16(Bb + (size_t)(srow + lrow) * K + k0 + lcol,      &Bs[srow * 32]);
    gld_lds16(Bb + (size_t)(srow + 16 + lrow) * K + k0 + lcol, &Bs[(srow + 16) * 32]);
    __syncthreads();

    bf16x8 af[4], bfr[4];
#pragma unroll
    for (int i = 0; i < 4; i++)
      af[i] = *(const bf16x8*)&As[(wm + i * 16 + l16) * 32 + quad * 8];
#pragma unroll
    for (int j = 0; j < 4; j++)
      bfr[j] = *(const bf16x8*)&Bs[(wn + j * 16 + l16) * 32 + quad * 8];
#pragma unroll
    for (int i = 0; i < 4; i++)
#pragma unroll
      for (int j = 0; j < 4; j++)
        acc[i][j] = __builtin_amdgcn_mfma_f32_16x16x32_bf16(af[i], bfr[j], acc[i][j], 0, 0, 0);
  }

#pragma unroll
  for (int i = 0; i < 4; i++)
#pragma unroll
    for (int j = 0; j < 4; j++) {
      int gm0 = bm + wm + i * 16 + quad * 4;
      int gn  = bn + wn + j * 16 + l16;
#pragma unroll
      for (int r = 0; r < 4; r++) {
        int gm = gm0 + r;
        float v = acc[i][j][r];
        if (mode == 0) {
          if (gn < QDIM) oq[(size_t)gm * QDIM + gn] = __float2bfloat16(v);
          else           ou[(size_t)gm * DKV + (gn - QDIM)] = __float2bfloat16(v);
        } else {
          oc[(size_t)gm * N + gn] = v;
        }
      }
    }
}

// ---------------------------------------------------------------------------
// x_dbl / delta / scan kernels (unchanged from round 5 — verified).
// ---------------------------------------------------------------------------
__global__ __launch_bounds__(128) void xdbl_kernel(
    const bf16* __restrict__ u, const void* __restrict__ xpw,
    const int* __restrict__ dflag, float* __restrict__ xd)
{
  __shared__ float us[DKV];
  const int t = blockIdx.x, tid = threadIdx.x;
  const int f = dflag[0];
  const bf16* ur = u + (size_t)t * DKV;
  for (int i = tid; i < DKV; i += 128) us[i] = bf2f(ur[i]);
  __syncthreads();
  if (tid < 96) {
    float acc = 0.f;
    const size_t wb = (size_t)tid * DKV;
    for (int k = 0; k < DKV; k += 8) {
      F8 w = load8(xpw, wb + k, f);
#pragma unroll
      for (int j = 0; j < 8; j++) acc = fmaf(w.v[j], us[k + j], acc);
    }
    xd[(size_t)t * 96 + tid] = acc;
  }
}

__global__ __launch_bounds__(256) void delta_kernel(
    const float* __restrict__ xd, const void* __restrict__ dtw,
    const void* __restrict__ dtb, const int* __restrict__ dflag,
    bf16* __restrict__ delta)
{
  __shared__ float dts[DTR];
  const int t = blockIdx.x, tid = threadIdx.x;
  const int f = dflag[0];
  if (tid < DTR) dts[tid] = xd[(size_t)t * 96 + tid];
  __syncthreads();
  for (int d = tid; d < DKV; d += 256) {
    float acc = load1(dtb, d, f);
    const size_t wb = (size_t)d * DTR;
#pragma unroll
    for (int k = 0; k < DTR; k += 8) {
      F8 w = load8(dtw, wb + k, f);
#pragma unroll
      for (int j = 0; j < 8; j++) acc = fmaf(w.v[j], dts[k + j], acc);
    }
    float sp = fmaxf(acc, 0.f) + log1pf(expf(-fabsf(acc)));
    delta[(size_t)t * DKV + d] = __float2bfloat16(sp);
  }
}

__global__ __launch_bounds__(256) void scan_pass1(
    const bf16* __restrict__ delta, const bf16* __restrict__ u,
    const float* __restrict__ xd, const void* __restrict__ A_log,
    const int* __restrict__ dflag, float* __restrict__ Pb, float* __restrict__ Hl)
{
  const int gid = blockIdx.x * 256 + threadIdx.x;
  const int c = gid >> 14;
  const int r = gid & 16383;
  const int d = r >> 4, n = r & 15;
  const int f = dflag[0];
  const float A = -expf(load1(A_log, d * NST + n, f));
  float p = 1.f, h = 0.f;
  const int t0 = c * CLEN;
  for (int tt = 0; tt < CLEN; tt++) {
    int t = t0 + tt;
    float dl = bf2f(delta[(size_t)t * DKV + d]);
    float uu = bf2f(u[(size_t)t * DKV + d]);
    float bm = xd[(size_t)t * 96 + DTR + n];
    float a = expf(dl * A);
    h = a * h + dl * bm * uu;
    p *= a;
  }
  Pb[gid] = p;
  Hl[gid] = h;
}

__global__ __launch_bounds__(256) void scan_combine(
    float* __restrict__ Pb, const float* __restrict__ Hl)
{
  const int idx = blockIdx.x * 256 + threadIdx.x;
  float run = 0.f;
  for (int c = 0; c < NCHUNK; c++) {
    size_t off = (size_t)c * 16384 + idx;
    float p = Pb[off], hl = Hl[off];
    Pb[off] = run;
    run = p * run + hl;
  }
}

__global__ __launch_bounds__(256) void scan_pass2(
    const bf16* __restrict__ delta, bf16* __restrict__ u,
    const float* __restrict__ xd, const void* __restrict__ A_log,
    const void* __restrict__ Dp, const int* __restrict__ dflag,
    const float* __restrict__ Hin)
{
  const int gid = blockIdx.x * 256 + threadIdx.x;
  const int c = gid >> 14;
  const int r = gid & 16383;
  const int d = r >> 4, n = r & 15;
  const int f = dflag[0];
  const float A = -expf(load1(A_log, d * NST + n, f));
  const float dpar = load1(Dp, d, f);
  float h = Hin[gid];
  const int t0 = c * CLEN;
  for (int tt = 0; tt < CLEN; tt++) {
    int t = t0 + tt;
    float dl = bf2f(delta[(size_t)t * DKV + d]);
    float uu = bf2f(u[(size_t)t * DKV + d]);
    float bm = xd[(size_t)t * 96 + DTR + n];
    float cm = xd[(size_t)t * 96 + DTR + NST + n];
    float a = expf(dl * A);
    h = a * h + dl * bm * uu;
    float part = h * cm;
    part += __shfl_xor(part, 1);
    part += __shfl_xor(part, 2);
    part += __shfl_xor(part, 4);
    part += __shfl_xor(part, 8);
    if (n == 0) u[(size_t)t * DKV + d] = __float2bfloat16(part + dpar * uu);
  }
}

// ---------------------------------------------------------------------------
// V transpose: vt[gd][t] = kv[t][KDIM + gd], gd in [0,512). LDS tile 64x64.
// ---------------------------------------------------------------------------
__global__ __launch_bounds__(256) void vtrans(
    const bf16* __restrict__ kv, unsigned short* __restrict__ vt)
{
  __shared__ float tile[64][68];
  const int tt0 = blockIdx.x * 64, d0 = blockIdx.y * 64;
  const int tid = threadIdx.x;
  for (int e = tid; e < 64 * 8; e += 256) {
    int row = e >> 3, c8 = (e & 7) * 8;           // row = t-offset, c8 = d-offset
    F8 v = load_b8(kv + (size_t)(tt0 + row) * DKV + KDIM + d0 + c8);
#pragma unroll
    for (int j = 0; j < 8; j++) tile[row][c8 + j] = v.v[j];
  }
  __syncthreads();
  for (int e = tid; e < 64 * 8; e += 256) {
    int dd = e >> 3, t8 = (e & 7) * 8;            // dd = d-offset, t8 = t-offset
    float vv[8];
#pragma unroll
    for (int j = 0; j < 8; j++) vv[j] = tile[t8 + j][dd];
    ushort4* o = (ushort4*)(vt + (size_t)(d0 + dd) * T_SEQ + tt0 + t8);
    o[0] = pack4(vv[0], vv[1], vv[2], vv[3]);
    o[1] = pack4(vv[4], vv[5], vv[6], vv[7]);
  }
}

// ---------------------------------------------------------------------------
// MFMA flash attention. Block = (64-q tile, head); 4 waves x 16 q-rows.
// K-chunk = 32 keys. S = Q*K^T (8 mfma), online softmax in C-layout,
// P -> per-wave LDS roundtrip (A-layout), O += P*V via V^T rows (8 mfma).
// Row pads: Qs/Ks 136, Vt/Ps 40 (16B-aligned, ~2-way banks).
// ---------------------------------------------------------------------------
__global__ __launch_bounds__(256) void attn_mfma(
    const bf16* __restrict__ q, const bf16* __restrict__ kv,
    const unsigned short* __restrict__ vt, bf16* __restrict__ y)
{
  __shared__ unsigned short Qs[64 * 136];
  __shared__ unsigned short Ks[32 * 136];
  __shared__ unsigned short Vts[128 * 40];
  __shared__ unsigned short Ps[4][16 * 40];
  const int tid = threadIdx.x;
  const int wave = tid >> 6, lane = tid & 63;
  const int quad = lane >> 4, l16 = lane & 15;
  const int qt = blockIdx.x, h = blockIdx.y, kvh = h >> 2;
  const int t0 = qt * 64;
  const float scale = 0.088388347648318447f;  // 1/sqrt(128)

  for (int e = tid; e < 64 * 16; e += 256) {
    int row = e >> 4, c8 = (e & 15) * 8;
    *(uint4*)&Qs[row * 136 + c8] =
        *(const uint4*)(q + (size_t)(t0 + row) * QDIM + h * DH + c8);
  }

  float m_r[4], l_r[4];
  f32x4 O[8];
#pragma unroll
  for (int r = 0; r < 4; r++) { m_r[r] = -1e30f; l_r[r] = 0.f; }
#pragma unroll
  for (int dt = 0; dt < 8; dt++) O[dt] = f32x4{0.f, 0.f, 0.f, 0.f};

  const int kb_start = (t0 > WIN - 1) ? ((t0 - (WIN - 1)) >> 5) : 0;
  const int kb_end = (t0 + 63) >> 5;

  for (int kb = kb_start; kb <= kb_end; kb++) {
    __syncthreads();
    for (int e = tid; e < 512; e += 256) {       // K: 32 rows x 128
      int row = e >> 4, c8 = (e & 15) * 8;
      *(uint4*)&Ks[row * 136 + c8] =
          *(const uint4*)(kv + (size_t)(kb * 32 + row) * DKV + kvh * DH + c8);
    }
    for (int e = tid; e < 512; e += 256) {       // V^T: 128 rows x 32
      int row = e >> 2, c8 = (e & 3) * 8;
      *(uint4*)&Vts[row * 40 + c8] =
          *(const uint4*)(vt + (size_t)(kvh * DH + row) * T_SEQ + kb * 32 + c8);
    }
    __syncthreads();

    // S = Q*K^T : 2 col-tiles, 4 k-steps
    f32x4 S0 = f32x4{0.f, 0.f, 0.f, 0.f}, S1 = f32x4{0.f, 0.f, 0.f, 0.f};
#pragma unroll
    for (int s = 0; s < 4; s++) {
      bf16x8 a = *(const bf16x8*)&Qs[(wave * 16 + l16) * 136 + s * 32 + quad * 8];
      bf16x8 b0 = *(const bf16x8*)&Ks[(l16) * 136 + s * 32 + quad * 8];
      bf16x8 b1 = *(const bf16x8*)&Ks[(16 + l16) * 136 + s * 32 + quad * 8];
      S0 = __builtin_amdgcn_mfma_f32_16x16x32_bf16(a, b0, S0, 0, 0, 0);
      S1 = __builtin_amdgcn_mfma_f32_16x16x32_bf16(a, b1, S1, 0, 0, 0);
    }

    const int ka0 = kb * 32 + l16;
    const int ka1 = ka0 + 16;
    const bool full = (kb * 32 >= t0 + 63 - (WIN - 1)) && (kb * 32 + 31 <= t0);

    float alpha_r[4];
#pragma unroll
    for (int r = 0; r < 4; r++) {
      int qa = t0 + wave * 16 + quad * 4 + r;
      float v0 = S0[r] * scale, v1 = S1[r] * scale;
      bool x0 = true, x1 = true;
      if (!full) {
        x0 = (ka0 <= qa) && (ka0 > qa - WIN);
        x1 = (ka1 <= qa) && (ka1 > qa - WIN);
        if (!x0) v0 = -1e30f;
        if (!x1) v1 = -1e30f;
      }
      float rm = fmaxf(v0, v1);
      rm = fmaxf(rm, __shfl_xor(rm, 1));
      rm = fmaxf(rm, __shfl_xor(rm, 2));
      rm = fmaxf(rm, __shfl_xor(rm, 4));
      rm = fmaxf(rm, __shfl_xor(rm, 8));
      float mnew = fmaxf(m_r[r], rm);
      float al = __expf(m_r[r] - mnew);
      float p0 = x0 ? __expf(v0 - mnew) : 0.f;
      float p1 = x1 ? __expf(v1 - mnew) : 0.f;
      float rs = p0 + p1;
      rs += __shfl_xor(rs, 1);
      rs += __shfl_xor(rs, 2);
      rs += __shfl_xor(rs, 4);
      rs += __shfl_xor(rs, 8);
      l_r[r] = l_r[r] * al + rs;
      m_r[r] = mnew;
      alpha_r[r] = al;
      Ps[wave][(quad * 4 + r) * 40 + l16]      = f2b_bits(p0);
      Ps[wave][(quad * 4 + r) * 40 + 16 + l16] = f2b_bits(p1);
    }
#pragma unroll
    for (int dt = 0; dt < 8; dt++)
#pragma unroll
      for (int r = 0; r < 4; r++) O[dt][r] *= alpha_r[r];

    // O += P*V  (P rows from own wave's LDS; V^T rows as B-frags)
    bf16x8 pa = *(const bf16x8*)&Ps[wave][l16 * 40 + quad * 8];
#pragma unroll
    for (int dt = 0; dt < 8; dt++) {
      bf16x8 b = *(const bf16x8*)&Vts[(dt * 16 + l16) * 40 + quad * 8];
      O[dt] = __builtin_amdgcn_mfma_f32_16x16x32_bf16(pa, b, O[dt], 0, 0, 0);
    }
  }

  float inv[4];
#pragma unroll
  for (int r = 0; r < 4; r++) inv[r] = 1.f / l_r[r];
#pragma unroll
  for (int dt = 0; dt < 8; dt++)
#pragma unroll
    for (int r = 0; r < 4; r++) {
      int row = t0 + wave * 16 + quad * 4 + r;
      y[(size_t)row * QDIM + h * DH + dt * 16 + l16] = __float2bfloat16(O[dt][r] * inv[r]);
    }
}

// ---------------------------------------------------------------------------
extern "C" void kernel_launch(void* const* d_in, const int* in_sizes, int n_in,
                              void* d_out, int out_size, void* d_ws, size_t ws_size,
                              hipStream_t stream)
{
  const void* x      = d_in[0];
  const void* W_attn = d_in[1];
  const void* A_log  = d_in[2];
  const void* xpw    = d_in[3];
  const void* dtw    = d_in[4];
  const void* dtb    = d_in[5];
  const void* Dp     = d_in[6];
  const void* W_o    = d_in[7];

  // Workspace, TOTAL ~68 MiB (round-2/3 evidence: 98 MB was valid):
  char* ws = (char*)d_ws;
  int*   dflag = (int*)ws;   ws += 256;
  bf16*  u     = (bf16*)ws;  ws += (size_t)T_SEQ * DKV * 2;        // 8.4 MB, becomes kv in-place
  float* xd    = (float*)ws; ws += (size_t)T_SEQ * 96 * 4;         // 1.6 MB
  char*  yreg  = ws;                                                // y aliases delta+Pb+Hl (16.78 MB)
  bf16*  delta = (bf16*)ws;  ws += (size_t)T_SEQ * DKV * 2;        // 8.4 MB
  float* Pb    = (float*)ws; ws += (size_t)NCHUNK * DKV * NST * 4; // 4.2 MB (becomes Hin)
  float* Hl    = (float*)ws; ws += (size_t)NCHUNK * DKV * NST * 4; // 4.2 MB
  unsigned short* x_bf  = (unsigned short*)ws; ws += (size_t)T_SEQ * NEMBD * 2;  // 16.8 MB
  unsigned short* wa_bf = (unsigned short*)ws; ws += (size_t)QKVD * NEMBD * 2;   // 12.6 MB
  unsigned short* wo_bf = (unsigned short*)ws; ws += (size_t)NEMBD * QDIM * 2;   //  8.4 MB
  unsigned short* vt    = (unsigned short*)ws; ws += (size_t)KDIM * T_SEQ * 2;   //  4.2 MB
  bf16*  y     = (bf16*)yreg;

  bf16*  q_bf = (bf16*)d_out;   // q parks in d_out until gemm2 overwrites it
  float* out  = (float*)d_out;

  detect_dtype<<<1, 64, 0, stream>>>((const unsigned short*)x, dflag);
  cvt_bf16<<<(T_SEQ * NEMBD / 8 + 255) / 256, 256, 0, stream>>>(x, dflag, x_bf, T_SEQ * NEMBD / 8);
  cvt_bf16<<<(QKVD * NEMBD / 8 + 255) / 256, 256, 0, stream>>>(W_attn, dflag, wa_bf, QKVD * NEMBD / 8);
  cvt_bf16<<<(NEMBD * QDIM / 8 + 255) / 256, 256, 0, stream>>>(W_o, dflag, wo_bf, NEMBD * QDIM / 8);

  gemm_mfma<<<dim3(QKVD / 128, T_SEQ / 128), 256, 0, stream>>>(
      x_bf, wa_bf, T_SEQ, QKVD, NEMBD, 0, q_bf, u, nullptr);
  xdbl_kernel<<<T_SEQ, 128, 0, stream>>>(u, xpw, dflag, xd);
  delta_kernel<<<T_SEQ, 256, 0, stream>>>(xd, dtw, dtb, dflag, delta);
  scan_pass1<<<4096, 256, 0, stream>>>(delta, u, xd, A_log, dflag, Pb, Hl);
  scan_combine<<<64, 256, 0, stream>>>(Pb, Hl);
  scan_pass2<<<4096, 256, 0, stream>>>(delta, u, xd, A_log, Dp, dflag, Pb);
  vtrans<<<dim3(T_SEQ / 64, KDIM / 64), 256, 0, stream>>>(u, vt);
  attn_mfma<<<dim3(T_SEQ / 64, NH), 256, 0, stream>>>(q_bf, u, vt, y);
  gemm_mfma<<<dim3(QDIM / 128, T_SEQ / 128), 256, 0, stream>>>(
      (const unsigned short*)y, wo_bf, T_SEQ, QDIM, QDIM, 1, nullptr, nullptr, out);
}

// Round 7
// 626.566 us; speedup vs baseline: 3.0434x; 1.2668x over previous
//
#include <hip/hip_runtime.h>
#include <hip/hip_bf16.h>

typedef __hip_bfloat16 bf16;
typedef __attribute__((ext_vector_type(8))) short bf16x8;   // 8 bf16 = 4 VGPRs
typedef __attribute__((ext_vector_type(4))) float f32x4;

#define T_SEQ 4096
#define NEMBD 2048
#define QKVD  3072
#define QDIM  2048
#define DKV   1024
#define KDIM  512
#define NH    16
#define DH    128
#define NST   16
#define DTR   64
#define WIN   512
#define NCHUNK 64
#define CLEN   64

__device__ inline float bf2f(bf16 x) { return __bfloat162float(x); }

struct F8 { float v[8]; };

// load 8 contiguous bf16 (16B) and widen to fp32 (bf16 bits << 16)
__device__ inline F8 load_b8(const bf16* p) {
  union { uint4 q; unsigned short s[8]; } u;
  u.q = *reinterpret_cast<const uint4*>(p);
  F8 r;
#pragma unroll
  for (int i = 0; i < 8; i++) r.v[i] = __uint_as_float((unsigned)u.s[i] << 16);
  return r;
}

// load 8 elements [idx, idx+8) from an INPUT array whose real dtype is
// bf16 (f32flag=0) or fp32 (f32flag=1). idx must be a multiple of 4.
__device__ inline F8 load8(const void* base, size_t idx, int f32flag) {
  if (f32flag) {
    const float4* p = reinterpret_cast<const float4*>((const float*)base + idx);
    float4 a = p[0], b = p[1];
    F8 r;
    r.v[0]=a.x; r.v[1]=a.y; r.v[2]=a.z; r.v[3]=a.w;
    r.v[4]=b.x; r.v[5]=b.y; r.v[6]=b.z; r.v[7]=b.w;
    return r;
  }
  return load_b8((const bf16*)base + idx);
}

__device__ inline float load1(const void* base, size_t idx, int f32flag) {
  return f32flag ? ((const float*)base)[idx] : bf2f(((const bf16*)base)[idx]);
}

__device__ inline unsigned short f2b_bits(float f) {
  bf16 h = __float2bfloat16(f);  // RNE
  union { bf16 h; unsigned short u; } c; c.h = h; return c.u;
}

__device__ inline ushort4 pack4(float a, float b, float c, float d) {
  ushort4 r; r.x = f2b_bits(a); r.y = f2b_bits(b); r.z = f2b_bits(c); r.w = f2b_bits(d);
  return r;
}

// async global->LDS, 16B per lane; LDS dest is wave-uniform base + lane*16.
__device__ inline void gld_lds16(const void* g, void* l) {
  __builtin_amdgcn_global_load_lds(
      (const __attribute__((address_space(1))) unsigned int*)g,
      (__attribute__((address_space(3))) unsigned int*)l, 16, 0, 0);
}

// ---------------------------------------------------------------------------
// Input-dtype detection (round-1/2 evidence: fp32; keep the hedge, zero cost).
// ---------------------------------------------------------------------------
__global__ void detect_dtype(const unsigned short* __restrict__ x, int* __restrict__ flag) {
  if (threadIdx.x == 0 && blockIdx.x == 0) {
    int c = 0;
    for (int i = 0; i < 128; i++) {
      float v = __uint_as_float((unsigned)x[i] << 16);
      float a = fabsf(v);
      if (a >= 1e-8f && a <= 1e4f) c++;
    }
    flag[0] = (c >= 120) ? 0 : 1;
  }
}

// convert n8*8 elements (fp32 or bf16 per dflag) -> packed bf16 bits
__global__ __launch_bounds__(256) void cvt_bf16(
    const void* __restrict__ in, const int* __restrict__ dflag,
    unsigned short* __restrict__ out, int n8)
{
  int i = blockIdx.x * 256 + threadIdx.x;
  if (i >= n8) return;
  const int f = dflag[0];
  F8 v = load8(in, (size_t)i * 8, f);
  ushort4* o = (ushort4*)(out + (size_t)i * 8);
  o[0] = pack4(v.v[0], v.v[1], v.v[2], v.v[3]);
  o[1] = pack4(v.v[4], v.v[5], v.v[6], v.v[7]);
}

// ---------------------------------------------------------------------------
// MFMA GEMM (unchanged — verified).
// ---------------------------------------------------------------------------
__global__ __launch_bounds__(256) void gemm_mfma(
    const unsigned short* __restrict__ A, const unsigned short* __restrict__ B,
    int M, int N, int K, int mode,
    bf16* __restrict__ oq, bf16* __restrict__ ou, float* __restrict__ oc)
{
  __shared__ unsigned short As[128 * 32];
  __shared__ unsigned short Bs[128 * 32];
  const int tid = threadIdx.x;
  const int wave = tid >> 6, lane = tid & 63;
  const int quad = lane >> 4, l16 = lane & 15;
  const int bm = blockIdx.y * 128, bn = blockIdx.x * 128;
  const int wm = (wave >> 1) * 64, wn = (wave & 1) * 64;

  const int srow = wave * 32;
  const int lrow = lane >> 2;
  const int lcol = (lane & 3) * 8;

  f32x4 acc[4][4];
#pragma unroll
  for (int i = 0; i < 4; i++)
#pragma unroll
    for (int j = 0; j < 4; j++) acc[i][j] = f32x4{0.f, 0.f, 0.f, 0.f};

  const unsigned short* Ab = A + (size_t)bm * K;
  const unsigned short* Bb = B + (size_t)bn * K;

  for (int k0 = 0; k0 < K; k0 += 32) {
    __syncthreads();
    gld_lds16(Ab + (size_t)(srow + lrow) * K + k0 + lcol,      &As[srow * 32]);
    gld_lds16(Ab + (size_t)(srow + 16 + lrow) * K + k0 + lcol, &As[(srow + 16) * 32]);
    gld_lds16(Bb + (size_t)(srow + lrow) * K + k0 + lcol,      &Bs[srow * 32]);
    gld_lds16(Bb + (size_t)(srow + 16 + lrow) * K + k0 + lcol, &Bs[(srow + 16) * 32]);
    __syncthreads();

    bf16x8 af[4], bfr[4];
#pragma unroll
    for (int i = 0; i < 4; i++)
      af[i] = *(const bf16x8*)&As[(wm + i * 16 + l16) * 32 + quad * 8];
#pragma unroll
    for (int j = 0; j < 4; j++)
      bfr[j] = *(const bf16x8*)&Bs[(wn + j * 16 + l16) * 32 + quad * 8];
#pragma unroll
    for (int i = 0; i < 4; i++)
#pragma unroll
      for (int j = 0; j < 4; j++)
        acc[i][j] = __builtin_amdgcn_mfma_f32_16x16x32_bf16(af[i], bfr[j], acc[i][j], 0, 0, 0);
  }

#pragma unroll
  for (int i = 0; i < 4; i++)
#pragma unroll
    for (int j = 0; j < 4; j++) {
      int gm0 = bm + wm + i * 16 + quad * 4;
      int gn  = bn + wn + j * 16 + l16;
#pragma unroll
      for (int r = 0; r < 4; r++) {
        int gm = gm0 + r;
        float v = acc[i][j][r];
        if (mode == 0) {
          if (gn < QDIM) oq[(size_t)gm * QDIM + gn] = __float2bfloat16(v);
          else           ou[(size_t)gm * DKV + (gn - QDIM)] = __float2bfloat16(v);
        } else {
          oc[(size_t)gm * N + gn] = v;
        }
      }
    }
}

// ---------------------------------------------------------------------------
// xdbl via MFMA: xd[4096,96] = u[4096,1024] * xpw[96,1024]^T.
// Block = 256 thr (4 waves) x 64 t-rows; wave -> 16 rows x 6 col-tiles.
// Register-prefetch next K-chunk to overlap global latency with MFMA.
// ---------------------------------------------------------------------------
__global__ __launch_bounds__(256) void xdbl_mfma(
    const bf16* __restrict__ u, const unsigned short* __restrict__ xpw_bf,
    float* __restrict__ xd)
{
  __shared__ unsigned short Us[64 * 32];
  __shared__ unsigned short Ws[96 * 32];
  const int tid = threadIdx.x;
  const int wave = tid >> 6, lane = tid & 63;
  const int quad = lane >> 4, l16 = lane & 15;
  const int t0 = blockIdx.x * 64;
  const unsigned short* ub = (const unsigned short*)u;

  f32x4 acc[6];
#pragma unroll
  for (int j = 0; j < 6; j++) acc[j] = f32x4{0.f, 0.f, 0.f, 0.f};

  const int urow = tid >> 2, ucol = (tid & 3) * 8;     // 64 rows x 32
  const int wrow0 = tid >> 2, wcol0 = (tid & 3) * 8;   // chunk tid   (rows 0..63)
  const int wrow1 = (256 + tid) >> 2;                  // chunk tid+256 (rows 64..95), tid<128

  uint4 upre = *(const uint4*)(ub + (size_t)(t0 + urow) * DKV + ucol);
  uint4 wpre0 = *(const uint4*)(xpw_bf + (size_t)wrow0 * DKV + wcol0);
  uint4 wpre1 = (tid < 128) ? *(const uint4*)(xpw_bf + (size_t)wrow1 * DKV + wcol0)
                            : uint4{0, 0, 0, 0};

  for (int k0 = 0; k0 < DKV; k0 += 32) {
    __syncthreads();
    *(uint4*)&Us[urow * 32 + ucol] = upre;
    *(uint4*)&Ws[wrow0 * 32 + wcol0] = wpre0;
    if (tid < 128) *(uint4*)&Ws[wrow1 * 32 + wcol0] = wpre1;
    __syncthreads();

    int kn = (k0 + 32 < DKV) ? (k0 + 32) : k0;   // guarded prefetch
    upre  = *(const uint4*)(ub + (size_t)(t0 + urow) * DKV + kn + ucol);
    wpre0 = *(const uint4*)(xpw_bf + (size_t)wrow0 * DKV + kn + wcol0);
    if (tid < 128) wpre1 = *(const uint4*)(xpw_bf + (size_t)wrow1 * DKV + kn + wcol0);

    bf16x8 a = *(const bf16x8*)&Us[(wave * 16 + l16) * 32 + quad * 8];
#pragma unroll
    for (int j = 0; j < 6; j++) {
      bf16x8 b = *(const bf16x8*)&Ws[(j * 16 + l16) * 32 + quad * 8];
      acc[j] = __builtin_amdgcn_mfma_f32_16x16x32_bf16(a, b, acc[j], 0, 0, 0);
    }
  }

#pragma unroll
  for (int j = 0; j < 6; j++)
#pragma unroll
    for (int r = 0; r < 4; r++) {
      int t = t0 + wave * 16 + quad * 4 + r;
      xd[(size_t)t * 96 + j * 16 + l16] = acc[j][r];
    }
}

// ---------------------------------------------------------------------------
// delta / scan kernels (unchanged — verified).
// ---------------------------------------------------------------------------
__global__ __launch_bounds__(256) void delta_kernel(
    const float* __restrict__ xd, const void* __restrict__ dtw,
    const void* __restrict__ dtb, const int* __restrict__ dflag,
    bf16* __restrict__ delta)
{
  __shared__ float dts[DTR];
  const int t = blockIdx.x, tid = threadIdx.x;
  const int f = dflag[0];
  if (tid < DTR) dts[tid] = xd[(size_t)t * 96 + tid];
  __syncthreads();
  for (int d = tid; d < DKV; d += 256) {
    float acc = load1(dtb, d, f);
    const size_t wb = (size_t)d * DTR;
#pragma unroll
    for (int k = 0; k < DTR; k += 8) {
      F8 w = load8(dtw, wb + k, f);
#pragma unroll
      for (int j = 0; j < 8; j++) acc = fmaf(w.v[j], dts[k + j], acc);
    }
    float sp = fmaxf(acc, 0.f) + log1pf(expf(-fabsf(acc)));
    delta[(size_t)t * DKV + d] = __float2bfloat16(sp);
  }
}

__global__ __launch_bounds__(256) void scan_pass1(
    const bf16* __restrict__ delta, const bf16* __restrict__ u,
    const float* __restrict__ xd, const void* __restrict__ A_log,
    const int* __restrict__ dflag, float* __restrict__ Pb, float* __restrict__ Hl)
{
  const int gid = blockIdx.x * 256 + threadIdx.x;
  const int c = gid >> 14;
  const int r = gid & 16383;
  const int d = r >> 4, n = r & 15;
  const int f = dflag[0];
  const float A = -expf(load1(A_log, d * NST + n, f));
  float p = 1.f, h = 0.f;
  const int t0 = c * CLEN;
  for (int tt = 0; tt < CLEN; tt++) {
    int t = t0 + tt;
    float dl = bf2f(delta[(size_t)t * DKV + d]);
    float uu = bf2f(u[(size_t)t * DKV + d]);
    float bm = xd[(size_t)t * 96 + DTR + n];
    float a = expf(dl * A);
    h = a * h + dl * bm * uu;
    p *= a;
  }
  Pb[gid] = p;
  Hl[gid] = h;
}

__global__ __launch_bounds__(256) void scan_combine(
    float* __restrict__ Pb, const float* __restrict__ Hl)
{
  const int idx = blockIdx.x * 256 + threadIdx.x;
  float run = 0.f;
  for (int c = 0; c < NCHUNK; c++) {
    size_t off = (size_t)c * 16384 + idx;
    float p = Pb[off], hl = Hl[off];
    Pb[off] = run;
    run = p * run + hl;
  }
}

__global__ __launch_bounds__(256) void scan_pass2(
    const bf16* __restrict__ delta, bf16* __restrict__ u,
    const float* __restrict__ xd, const void* __restrict__ A_log,
    const void* __restrict__ Dp, const int* __restrict__ dflag,
    const float* __restrict__ Hin)
{
  const int gid = blockIdx.x * 256 + threadIdx.x;
  const int c = gid >> 14;
  const int r = gid & 16383;
  const int d = r >> 4, n = r & 15;
  const int f = dflag[0];
  const float A = -expf(load1(A_log, d * NST + n, f));
  const float dpar = load1(Dp, d, f);
  float h = Hin[gid];
  const int t0 = c * CLEN;
  for (int tt = 0; tt < CLEN; tt++) {
    int t = t0 + tt;
    float dl = bf2f(delta[(size_t)t * DKV + d]);
    float uu = bf2f(u[(size_t)t * DKV + d]);
    float bm = xd[(size_t)t * 96 + DTR + n];
    float cm = xd[(size_t)t * 96 + DTR + NST + n];
    float a = expf(dl * A);
    h = a * h + dl * bm * uu;
    float part = h * cm;
    part += __shfl_xor(part, 1);
    part += __shfl_xor(part, 2);
    part += __shfl_xor(part, 4);
    part += __shfl_xor(part, 8);
    if (n == 0) u[(size_t)t * DKV + d] = __float2bfloat16(part + dpar * uu);
  }
}

// ---------------------------------------------------------------------------
// V transpose (unchanged).
// ---------------------------------------------------------------------------
__global__ __launch_bounds__(256) void vtrans(
    const bf16* __restrict__ kv, unsigned short* __restrict__ vt)
{
  __shared__ float tile[64][68];
  const int tt0 = blockIdx.x * 64, d0 = blockIdx.y * 64;
  const int tid = threadIdx.x;
  for (int e = tid; e < 64 * 8; e += 256) {
    int row = e >> 3, c8 = (e & 7) * 8;
    F8 v = load_b8(kv + (size_t)(tt0 + row) * DKV + KDIM + d0 + c8);
#pragma unroll
    for (int j = 0; j < 8; j++) tile[row][c8 + j] = v.v[j];
  }
  __syncthreads();
  for (int e = tid; e < 64 * 8; e += 256) {
    int dd = e >> 3, t8 = (e & 7) * 8;
    float vv[8];
#pragma unroll
    for (int j = 0; j < 8; j++) vv[j] = tile[t8 + j][dd];
    ushort4* o = (ushort4*)(vt + (size_t)(d0 + dd) * T_SEQ + tt0 + t8);
    o[0] = pack4(vv[0], vv[1], vv[2], vv[3]);
    o[1] = pack4(vv[4], vv[5], vv[6], vv[7]);
  }
}

// ---------------------------------------------------------------------------
// MFMA flash attention (unchanged — verified).
// ---------------------------------------------------------------------------
__global__ __launch_bounds__(256) void attn_mfma(
    const bf16* __restrict__ q, const bf16* __restrict__ kv,
    const unsigned short* __restrict__ vt, bf16* __restrict__ y)
{
  __shared__ unsigned short Qs[64 * 136];
  __shared__ unsigned short Ks[32 * 136];
  __shared__ unsigned short Vts[128 * 40];
  __shared__ unsigned short Ps[4][16 * 40];
  const int tid = threadIdx.x;
  const int wave = tid >> 6, lane = tid & 63;
  const int quad = lane >> 4, l16 = lane & 15;
  const int qt = blockIdx.x, h = blockIdx.y, kvh = h >> 2;
  const int t0 = qt * 64;
  const float scale = 0.088388347648318447f;

  for (int e = tid; e < 64 * 16; e += 256) {
    int row = e >> 4, c8 = (e & 15) * 8;
    *(uint4*)&Qs[row * 136 + c8] =
        *(const uint4*)(q + (size_t)(t0 + row) * QDIM + h * DH + c8);
  }

  float m_r[4], l_r[4];
  f32x4 O[8];
#pragma unroll
  for (int r = 0; r < 4; r++) { m_r[r] = -1e30f; l_r[r] = 0.f; }
#pragma unroll
  for (int dt = 0; dt < 8; dt++) O[dt] = f32x4{0.f, 0.f, 0.f, 0.f};

  const int kb_start = (t0 > WIN - 1) ? ((t0 - (WIN - 1)) >> 5) : 0;
  const int kb_end = (t0 + 63) >> 5;

  for (int kb = kb_start; kb <= kb_end; kb++) {
    __syncthreads();
    for (int e = tid; e < 512; e += 256) {
      int row = e >> 4, c8 = (e & 15) * 8;
      *(uint4*)&Ks[row * 136 + c8] =
          *(const uint4*)(kv + (size_t)(kb * 32 + row) * DKV + kvh * DH + c8);
    }
    for (int e = tid; e < 512; e += 256) {
      int row = e >> 2, c8 = (e & 3) * 8;
      *(uint4*)&Vts[row * 40 + c8] =
          *(const uint4*)(vt + (size_t)(kvh * DH + row) * T_SEQ + kb * 32 + c8);
    }
    __syncthreads();

    f32x4 S0 = f32x4{0.f, 0.f, 0.f, 0.f}, S1 = f32x4{0.f, 0.f, 0.f, 0.f};
#pragma unroll
    for (int s = 0; s < 4; s++) {
      bf16x8 a = *(const bf16x8*)&Qs[(wave * 16 + l16) * 136 + s * 32 + quad * 8];
      bf16x8 b0 = *(const bf16x8*)&Ks[(l16) * 136 + s * 32 + quad * 8];
      bf16x8 b1 = *(const bf16x8*)&Ks[(16 + l16) * 136 + s * 32 + quad * 8];
      S0 = __builtin_amdgcn_mfma_f32_16x16x32_bf16(a, b0, S0, 0, 0, 0);
      S1 = __builtin_amdgcn_mfma_f32_16x16x32_bf16(a, b1, S1, 0, 0, 0);
    }

    const int ka0 = kb * 32 + l16;
    const int ka1 = ka0 + 16;
    const bool full = (kb * 32 >= t0 + 63 - (WIN - 1)) && (kb * 32 + 31 <= t0);

    float alpha_r[4];
#pragma unroll
    for (int r = 0; r < 4; r++) {
      int qa = t0 + wave * 16 + quad * 4 + r;
      float v0 = S0[r] * scale, v1 = S1[r] * scale;
      bool x0 = true, x1 = true;
      if (!full) {
        x0 = (ka0 <= qa) && (ka0 > qa - WIN);
        x1 = (ka1 <= qa) && (ka1 > qa - WIN);
        if (!x0) v0 = -1e30f;
        if (!x1) v1 = -1e30f;
      }
      float rm = fmaxf(v0, v1);
      rm = fmaxf(rm, __shfl_xor(rm, 1));
      rm = fmaxf(rm, __shfl_xor(rm, 2));
      rm = fmaxf(rm, __shfl_xor(rm, 4));
      rm = fmaxf(rm, __shfl_xor(rm, 8));
      float mnew = fmaxf(m_r[r], rm);
      float al = __expf(m_r[r] - mnew);
      float p0 = x0 ? __expf(v0 - mnew) : 0.f;
      float p1 = x1 ? __expf(v1 - mnew) : 0.f;
      float rs = p0 + p1;
      rs += __shfl_xor(rs, 1);
      rs += __shfl_xor(rs, 2);
      rs += __shfl_xor(rs, 4);
      rs += __shfl_xor(rs, 8);
      l_r[r] = l_r[r] * al + rs;
      m_r[r] = mnew;
      alpha_r[r] = al;
      Ps[wave][(quad * 4 + r) * 40 + l16]      = f2b_bits(p0);
      Ps[wave][(quad * 4 + r) * 40 + 16 + l16] = f2b_bits(p1);
    }
#pragma unroll
    for (int dt = 0; dt < 8; dt++)
#pragma unroll
      for (int r = 0; r < 4; r++) O[dt][r] *= alpha_r[r];

    bf16x8 pa = *(const bf16x8*)&Ps[wave][l16 * 40 + quad * 8];
#pragma unroll
    for (int dt = 0; dt < 8; dt++) {
      bf16x8 b = *(const bf16x8*)&Vts[(dt * 16 + l16) * 40 + quad * 8];
      O[dt] = __builtin_amdgcn_mfma_f32_16x16x32_bf16(pa, b, O[dt], 0, 0, 0);
    }
  }

  float inv[4];
#pragma unroll
  for (int r = 0; r < 4; r++) inv[r] = 1.f / l_r[r];
#pragma unroll
  for (int dt = 0; dt < 8; dt++)
#pragma unroll
    for (int r = 0; r < 4; r++) {
      int row = t0 + wave * 16 + quad * 4 + r;
      y[(size_t)row * QDIM + h * DH + dt * 16 + l16] = __float2bfloat16(O[dt][r] * inv[r]);
    }
}

// ---------------------------------------------------------------------------
extern "C" void kernel_launch(void* const* d_in, const int* in_sizes, int n_in,
                              void* d_out, int out_size, void* d_ws, size_t ws_size,
                              hipStream_t stream)
{
  const void* x      = d_in[0];
  const void* W_attn = d_in[1];
  const void* A_log  = d_in[2];
  const void* xpw    = d_in[3];
  const void* dtw    = d_in[4];
  const void* dtb    = d_in[5];
  const void* Dp     = d_in[6];
  const void* W_o    = d_in[7];

  // Workspace, TOTAL ~69 MiB:
  char* ws = (char*)d_ws;
  int*   dflag = (int*)ws;   ws += 256;
  bf16*  u     = (bf16*)ws;  ws += (size_t)T_SEQ * DKV * 2;        // 8.4 MB, becomes kv in-place
  float* xd    = (float*)ws; ws += (size_t)T_SEQ * 96 * 4;         // 1.6 MB
  char*  yreg  = ws;                                                // y aliases delta+Pb+Hl (16.78 MB)
  bf16*  delta = (bf16*)ws;  ws += (size_t)T_SEQ * DKV * 2;        // 8.4 MB
  float* Pb    = (float*)ws; ws += (size_t)NCHUNK * DKV * NST * 4; // 4.2 MB (becomes Hin)
  float* Hl    = (float*)ws; ws += (size_t)NCHUNK * DKV * NST * 4; // 4.2 MB
  unsigned short* x_bf  = (unsigned short*)ws; ws += (size_t)T_SEQ * NEMBD * 2;  // 16.8 MB
  unsigned short* wa_bf = (unsigned short*)ws; ws += (size_t)QKVD * NEMBD * 2;   // 12.6 MB
  unsigned short* wo_bf = (unsigned short*)ws; ws += (size_t)NEMBD * QDIM * 2;   //  8.4 MB
  unsigned short* vt    = (unsigned short*)ws; ws += (size_t)KDIM * T_SEQ * 2;   //  4.2 MB
  unsigned short* xpw_bf = (unsigned short*)ws; ws += (size_t)96 * DKV * 2;      //  0.2 MB
  bf16*  y     = (bf16*)yreg;

  bf16*  q_bf = (bf16*)d_out;   // q parks in d_out until gemm2 overwrites it
  float* out  = (float*)d_out;

  detect_dtype<<<1, 64, 0, stream>>>((const unsigned short*)x, dflag);
  cvt_bf16<<<(T_SEQ * NEMBD / 8 + 255) / 256, 256, 0, stream>>>(x, dflag, x_bf, T_SEQ * NEMBD / 8);
  cvt_bf16<<<(QKVD * NEMBD / 8 + 255) / 256, 256, 0, stream>>>(W_attn, dflag, wa_bf, QKVD * NEMBD / 8);
  cvt_bf16<<<(NEMBD * QDIM / 8 + 255) / 256, 256, 0, stream>>>(W_o, dflag, wo_bf, NEMBD * QDIM / 8);
  cvt_bf16<<<(96 * DKV / 8 + 255) / 256, 256, 0, stream>>>(xpw, dflag, xpw_bf, 96 * DKV / 8);

  gemm_mfma<<<dim3(QKVD / 128, T_SEQ / 128), 256, 0, stream>>>(
      x_bf, wa_bf, T_SEQ, QKVD, NEMBD, 0, q_bf, u, nullptr);
  xdbl_mfma<<<T_SEQ / 64, 256, 0, stream>>>(u, xpw_bf, xd);
  delta_kernel<<<T_SEQ, 256, 0, stream>>>(xd, dtw, dtb, dflag, delta);
  scan_pass1<<<4096, 256, 0, stream>>>(delta, u, xd, A_log, dflag, Pb, Hl);
  scan_combine<<<64, 256, 0, stream>>>(Pb, Hl);
  scan_pass2<<<4096, 256, 0, stream>>>(delta, u, xd, A_log, Dp, dflag, Pb);
  vtrans<<<dim3(T_SEQ / 64, KDIM / 64), 256, 0, stream>>>(u, vt);
  attn_mfma<<<dim3(T_SEQ / 64, NH), 256, 0, stream>>>(q_bf, u, vt, y);
  gemm_mfma<<<dim3(QDIM / 128, T_SEQ / 128), 256, 0, stream>>>(
      (const unsigned short*)y, wo_bf, T_SEQ, QDIM, QDIM, 1, nullptr, nullptr, out);
}

// Round 8
// 547.809 us; speedup vs baseline: 3.4809x; 1.1438x over previous
//
#include <hip/hip_runtime.h>
#include <hip/hip_bf16.h>

typedef __hip_bfloat16 bf16;
typedef __attribute__((ext_vector_type(8))) short bf16x8;   // 8 bf16 = 4 VGPRs
typedef __attribute__((ext_vector_type(4))) float f32x4;

#define T_SEQ 4096
#define NEMBD 2048
#define QKVD  3072
#define QDIM  2048
#define DKV   1024
#define KDIM  512
#define NH    16
#define DH    128
#define NST   16
#define DTR   64
#define WIN   512
#define NCHUNK 64
#define CLEN   64

__device__ inline float bf2f(bf16 x) { return __bfloat162float(x); }

struct F8 { float v[8]; };

// load 8 contiguous bf16 (16B) and widen to fp32 (bf16 bits << 16)
__device__ inline F8 load_b8(const bf16* p) {
  union { uint4 q; unsigned short s[8]; } u;
  u.q = *reinterpret_cast<const uint4*>(p);
  F8 r;
#pragma unroll
  for (int i = 0; i < 8; i++) r.v[i] = __uint_as_float((unsigned)u.s[i] << 16);
  return r;
}

// load 8 elements [idx, idx+8) from an INPUT array whose real dtype is
// bf16 (f32flag=0) or fp32 (f32flag=1). idx must be a multiple of 4.
__device__ inline F8 load8(const void* base, size_t idx, int f32flag) {
  if (f32flag) {
    const float4* p = reinterpret_cast<const float4*>((const float*)base + idx);
    float4 a = p[0], b = p[1];
    F8 r;
    r.v[0]=a.x; r.v[1]=a.y; r.v[2]=a.z; r.v[3]=a.w;
    r.v[4]=b.x; r.v[5]=b.y; r.v[6]=b.z; r.v[7]=b.w;
    return r;
  }
  return load_b8((const bf16*)base + idx);
}

__device__ inline float load1(const void* base, size_t idx, int f32flag) {
  return f32flag ? ((const float*)base)[idx] : bf2f(((const bf16*)base)[idx]);
}

__device__ inline unsigned short f2b_bits(float f) {
  bf16 h = __float2bfloat16(f);  // RNE
  union { bf16 h; unsigned short u; } c; c.h = h; return c.u;
}

__device__ inline ushort4 pack4(float a, float b, float c, float d) {
  ushort4 r; r.x = f2b_bits(a); r.y = f2b_bits(b); r.z = f2b_bits(c); r.w = f2b_bits(d);
  return r;
}

// async global->LDS, 16B per lane; LDS dest is wave-uniform base + lane*16.
__device__ inline void gld_lds16(const void* g, void* l) {
  __builtin_amdgcn_global_load_lds(
      (const __attribute__((address_space(1))) unsigned int*)g,
      (__attribute__((address_space(3))) unsigned int*)l, 16, 0, 0);
}

// ---------------------------------------------------------------------------
// Input-dtype detection (round-1/2 evidence: fp32; keep the hedge, zero cost).
// ---------------------------------------------------------------------------
__global__ void detect_dtype(const unsigned short* __restrict__ x, int* __restrict__ flag) {
  if (threadIdx.x == 0 && blockIdx.x == 0) {
    int c = 0;
    for (int i = 0; i < 128; i++) {
      float v = __uint_as_float((unsigned)x[i] << 16);
      float a = fabsf(v);
      if (a >= 1e-8f && a <= 1e4f) c++;
    }
    flag[0] = (c >= 120) ? 0 : 1;
  }
}

// convert n8*8 elements (fp32 or bf16 per dflag) -> packed bf16 bits
__global__ __launch_bounds__(256) void cvt_bf16(
    const void* __restrict__ in, const int* __restrict__ dflag,
    unsigned short* __restrict__ out, int n8)
{
  int i = blockIdx.x * 256 + threadIdx.x;
  if (i >= n8) return;
  const int f = dflag[0];
  F8 v = load8(in, (size_t)i * 8, f);
  ushort4* o = (ushort4*)(out + (size_t)i * 8);
  o[0] = pack4(v.v[0], v.v[1], v.v[2], v.v[3]);
  o[1] = pack4(v.v[4], v.v[5], v.v[6], v.v[7]);
}

// ---------------------------------------------------------------------------
// MFMA GEMM (unchanged — verified).
// ---------------------------------------------------------------------------
__global__ __launch_bounds__(256) void gemm_mfma(
    const unsigned short* __restrict__ A, const unsigned short* __restrict__ B,
    int M, int N, int K, int mode,
    bf16* __restrict__ oq, bf16* __restrict__ ou, float* __restrict__ oc)
{
  __shared__ unsigned short As[128 * 32];
  __shared__ unsigned short Bs[128 * 32];
  const int tid = threadIdx.x;
  const int wave = tid >> 6, lane = tid & 63;
  const int quad = lane >> 4, l16 = lane & 15;
  const int bm = blockIdx.y * 128, bn = blockIdx.x * 128;
  const int wm = (wave >> 1) * 64, wn = (wave & 1) * 64;

  const int srow = wave * 32;
  const int lrow = lane >> 2;
  const int lcol = (lane & 3) * 8;

  f32x4 acc[4][4];
#pragma unroll
  for (int i = 0; i < 4; i++)
#pragma unroll
    for (int j = 0; j < 4; j++) acc[i][j] = f32x4{0.f, 0.f, 0.f, 0.f};

  const unsigned short* Ab = A + (size_t)bm * K;
  const unsigned short* Bb = B + (size_t)bn * K;

  for (int k0 = 0; k0 < K; k0 += 32) {
    __syncthreads();
    gld_lds16(Ab + (size_t)(srow + lrow) * K + k0 + lcol,      &As[srow * 32]);
    gld_lds16(Ab + (size_t)(srow + 16 + lrow) * K + k0 + lcol, &As[(srow + 16) * 32]);
    gld_lds16(Bb + (size_t)(srow + lrow) * K + k0 + lcol,      &Bs[srow * 32]);
    gld_lds16(Bb + (size_t)(srow + 16 + lrow) * K + k0 + lcol, &Bs[(srow + 16) * 32]);
    __syncthreads();

    bf16x8 af[4], bfr[4];
#pragma unroll
    for (int i = 0; i < 4; i++)
      af[i] = *(const bf16x8*)&As[(wm + i * 16 + l16) * 32 + quad * 8];
#pragma unroll
    for (int j = 0; j < 4; j++)
      bfr[j] = *(const bf16x8*)&Bs[(wn + j * 16 + l16) * 32 + quad * 8];
#pragma unroll
    for (int i = 0; i < 4; i++)
#pragma unroll
      for (int j = 0; j < 4; j++)
        acc[i][j] = __builtin_amdgcn_mfma_f32_16x16x32_bf16(af[i], bfr[j], acc[i][j], 0, 0, 0);
  }

#pragma unroll
  for (int i = 0; i < 4; i++)
#pragma unroll
    for (int j = 0; j < 4; j++) {
      int gm0 = bm + wm + i * 16 + quad * 4;
      int gn  = bn + wn + j * 16 + l16;
#pragma unroll
      for (int r = 0; r < 4; r++) {
        int gm = gm0 + r;
        float v = acc[i][j][r];
        if (mode == 0) {
          if (gn < QDIM) oq[(size_t)gm * QDIM + gn] = __float2bfloat16(v);
          else           ou[(size_t)gm * DKV + (gn - QDIM)] = __float2bfloat16(v);
        } else {
          oc[(size_t)gm * N + gn] = v;
        }
      }
    }
}

// ---------------------------------------------------------------------------
// xdbl via MFMA (unchanged from round 7 — verified).
// ---------------------------------------------------------------------------
__global__ __launch_bounds__(256) void xdbl_mfma(
    const bf16* __restrict__ u, const unsigned short* __restrict__ xpw_bf,
    float* __restrict__ xd)
{
  __shared__ unsigned short Us[64 * 32];
  __shared__ unsigned short Ws[96 * 32];
  const int tid = threadIdx.x;
  const int wave = tid >> 6, lane = tid & 63;
  const int quad = lane >> 4, l16 = lane & 15;
  const int t0 = blockIdx.x * 64;
  const unsigned short* ub = (const unsigned short*)u;

  f32x4 acc[6];
#pragma unroll
  for (int j = 0; j < 6; j++) acc[j] = f32x4{0.f, 0.f, 0.f, 0.f};

  const int urow = tid >> 2, ucol = (tid & 3) * 8;
  const int wrow0 = tid >> 2, wcol0 = (tid & 3) * 8;
  const int wrow1 = (256 + tid) >> 2;

  uint4 upre = *(const uint4*)(ub + (size_t)(t0 + urow) * DKV + ucol);
  uint4 wpre0 = *(const uint4*)(xpw_bf + (size_t)wrow0 * DKV + wcol0);
  uint4 wpre1 = (tid < 128) ? *(const uint4*)(xpw_bf + (size_t)wrow1 * DKV + wcol0)
                            : uint4{0, 0, 0, 0};

  for (int k0 = 0; k0 < DKV; k0 += 32) {
    __syncthreads();
    *(uint4*)&Us[urow * 32 + ucol] = upre;
    *(uint4*)&Ws[wrow0 * 32 + wcol0] = wpre0;
    if (tid < 128) *(uint4*)&Ws[wrow1 * 32 + wcol0] = wpre1;
    __syncthreads();

    int kn = (k0 + 32 < DKV) ? (k0 + 32) : k0;
    upre  = *(const uint4*)(ub + (size_t)(t0 + urow) * DKV + kn + ucol);
    wpre0 = *(const uint4*)(xpw_bf + (size_t)wrow0 * DKV + kn + wcol0);
    if (tid < 128) wpre1 = *(const uint4*)(xpw_bf + (size_t)wrow1 * DKV + kn + wcol0);

    bf16x8 a = *(const bf16x8*)&Us[(wave * 16 + l16) * 32 + quad * 8];
#pragma unroll
    for (int j = 0; j < 6; j++) {
      bf16x8 b = *(const bf16x8*)&Ws[(j * 16 + l16) * 32 + quad * 8];
      acc[j] = __builtin_amdgcn_mfma_f32_16x16x32_bf16(a, b, acc[j], 0, 0, 0);
    }
  }

#pragma unroll
  for (int j = 0; j < 6; j++)
#pragma unroll
    for (int r = 0; r < 4; r++) {
      int t = t0 + wave * 16 + quad * 4 + r;
      xd[(size_t)t * 96 + j * 16 + l16] = acc[j][r];
    }
}

// ---------------------------------------------------------------------------
// delta via MFMA: delta[4096,1024] = softplus(xd[:, :64] * dtw[1024,64]^T + dtb).
// Block = 256 thr (4 waves) x (64 t-rows x 128 d-cols); K=64 (2 chunks).
// Per wave: 16 rows x 8 col-tiles = 16 MFMAs, fused softplus epilogue.
// ---------------------------------------------------------------------------
__global__ __launch_bounds__(256) void delta_mfma(
    const float* __restrict__ xd, const unsigned short* __restrict__ dtw_bf,
    const void* __restrict__ dtb, const int* __restrict__ dflag,
    bf16* __restrict__ delta)
{
  __shared__ unsigned short Xs[64 * 72];
  __shared__ unsigned short Ws[128 * 72];
  const int tid = threadIdx.x;
  const int wave = tid >> 6, lane = tid & 63;
  const int quad = lane >> 4, l16 = lane & 15;
  const int t0 = blockIdx.y * 64, d0 = blockIdx.x * 128;

  for (int e = tid; e < 64 * 8; e += 256) {       // Xs: 64 rows x 64 k (fp32->bf16)
    int row = e >> 3, c8 = (e & 7) * 8;
    const float* p = xd + (size_t)(t0 + row) * 96 + c8;
    float4 a = *(const float4*)p, b = *(const float4*)(p + 4);
    *(ushort4*)&Xs[row * 72 + c8]     = pack4(a.x, a.y, a.z, a.w);
    *(ushort4*)&Xs[row * 72 + c8 + 4] = pack4(b.x, b.y, b.z, b.w);
  }
  for (int e = tid; e < 128 * 8; e += 256) {      // Ws: 128 rows x 64 k
    int row = e >> 3, c8 = (e & 7) * 8;
    *(uint4*)&Ws[row * 72 + c8] = *(const uint4*)(dtw_bf + (size_t)(d0 + row) * DTR + c8);
  }
  __syncthreads();

  bf16x8 a0 = *(const bf16x8*)&Xs[(wave * 16 + l16) * 72 + quad * 8];
  bf16x8 a1 = *(const bf16x8*)&Xs[(wave * 16 + l16) * 72 + 32 + quad * 8];

  f32x4 acc[8];
#pragma unroll
  for (int j = 0; j < 8; j++) {
    bf16x8 b0 = *(const bf16x8*)&Ws[(j * 16 + l16) * 72 + quad * 8];
    bf16x8 b1 = *(const bf16x8*)&Ws[(j * 16 + l16) * 72 + 32 + quad * 8];
    acc[j] = __builtin_amdgcn_mfma_f32_16x16x32_bf16(a0, b0, f32x4{0.f, 0.f, 0.f, 0.f}, 0, 0, 0);
    acc[j] = __builtin_amdgcn_mfma_f32_16x16x32_bf16(a1, b1, acc[j], 0, 0, 0);
  }

  const int f = dflag[0];
#pragma unroll
  for (int j = 0; j < 8; j++) {
    int d = d0 + j * 16 + l16;
    float bias = load1(dtb, d, f);
#pragma unroll
    for (int r = 0; r < 4; r++) {
      int t = t0 + wave * 16 + quad * 4 + r;
      float v = acc[j][r] + bias;
      float sp = fmaxf(v, 0.f) + log1pf(expf(-fabsf(v)));   // stable softplus
      delta[(size_t)t * DKV + d] = __float2bfloat16(sp);
    }
  }
}

// ---------------------------------------------------------------------------
// scan kernels (unchanged — verified).
// ---------------------------------------------------------------------------
__global__ __launch_bounds__(256) void scan_pass1(
    const bf16* __restrict__ delta, const bf16* __restrict__ u,
    const float* __restrict__ xd, const void* __restrict__ A_log,
    const int* __restrict__ dflag, float* __restrict__ Pb, float* __restrict__ Hl)
{
  const int gid = blockIdx.x * 256 + threadIdx.x;
  const int c = gid >> 14;
  const int r = gid & 16383;
  const int d = r >> 4, n = r & 15;
  const int f = dflag[0];
  const float A = -expf(load1(A_log, d * NST + n, f));
  float p = 1.f, h = 0.f;
  const int t0 = c * CLEN;
  for (int tt = 0; tt < CLEN; tt++) {
    int t = t0 + tt;
    float dl = bf2f(delta[(size_t)t * DKV + d]);
    float uu = bf2f(u[(size_t)t * DKV + d]);
    float bm = xd[(size_t)t * 96 + DTR + n];
    float a = expf(dl * A);
    h = a * h + dl * bm * uu;
    p *= a;
  }
  Pb[gid] = p;
  Hl[gid] = h;
}

__global__ __launch_bounds__(256) void scan_combine(
    float* __restrict__ Pb, const float* __restrict__ Hl)
{
  const int idx = blockIdx.x * 256 + threadIdx.x;
  float run = 0.f;
  for (int c = 0; c < NCHUNK; c++) {
    size_t off = (size_t)c * 16384 + idx;
    float p = Pb[off], hl = Hl[off];
    Pb[off] = run;
    run = p * run + hl;
  }
}

__global__ __launch_bounds__(256) void scan_pass2(
    const bf16* __restrict__ delta, bf16* __restrict__ u,
    const float* __restrict__ xd, const void* __restrict__ A_log,
    const void* __restrict__ Dp, const int* __restrict__ dflag,
    const float* __restrict__ Hin)
{
  const int gid = blockIdx.x * 256 + threadIdx.x;
  const int c = gid >> 14;
  const int r = gid & 16383;
  const int d = r >> 4, n = r & 15;
  const int f = dflag[0];
  const float A = -expf(load1(A_log, d * NST + n, f));
  const float dpar = load1(Dp, d, f);
  float h = Hin[gid];
  const int t0 = c * CLEN;
  for (int tt = 0; tt < CLEN; tt++) {
    int t = t0 + tt;
    float dl = bf2f(delta[(size_t)t * DKV + d]);
    float uu = bf2f(u[(size_t)t * DKV + d]);
    float bm = xd[(size_t)t * 96 + DTR + n];
    float cm = xd[(size_t)t * 96 + DTR + NST + n];
    float a = expf(dl * A);
    h = a * h + dl * bm * uu;
    float part = h * cm;
    part += __shfl_xor(part, 1);
    part += __shfl_xor(part, 2);
    part += __shfl_xor(part, 4);
    part += __shfl_xor(part, 8);
    if (n == 0) u[(size_t)t * DKV + d] = __float2bfloat16(part + dpar * uu);
  }
}

// ---------------------------------------------------------------------------
// V transpose (unchanged).
// ---------------------------------------------------------------------------
__global__ __launch_bounds__(256) void vtrans(
    const bf16* __restrict__ kv, unsigned short* __restrict__ vt)
{
  __shared__ float tile[64][68];
  const int tt0 = blockIdx.x * 64, d0 = blockIdx.y * 64;
  const int tid = threadIdx.x;
  for (int e = tid; e < 64 * 8; e += 256) {
    int row = e >> 3, c8 = (e & 7) * 8;
    F8 v = load_b8(kv + (size_t)(tt0 + row) * DKV + KDIM + d0 + c8);
#pragma unroll
    for (int j = 0; j < 8; j++) tile[row][c8 + j] = v.v[j];
  }
  __syncthreads();
  for (int e = tid; e < 64 * 8; e += 256) {
    int dd = e >> 3, t8 = (e & 7) * 8;
    float vv[8];
#pragma unroll
    for (int j = 0; j < 8; j++) vv[j] = tile[t8 + j][dd];
    ushort4* o = (ushort4*)(vt + (size_t)(d0 + dd) * T_SEQ + tt0 + t8);
    o[0] = pack4(vv[0], vv[1], vv[2], vv[3]);
    o[1] = pack4(vv[4], vv[5], vv[6], vv[7]);
  }
}

// ---------------------------------------------------------------------------
// MFMA flash attention (unchanged — verified).
// ---------------------------------------------------------------------------
__global__ __launch_bounds__(256) void attn_mfma(
    const bf16* __restrict__ q, const bf16* __restrict__ kv,
    const unsigned short* __restrict__ vt, bf16* __restrict__ y)
{
  __shared__ unsigned short Qs[64 * 136];
  __shared__ unsigned short Ks[32 * 136];
  __shared__ unsigned short Vts[128 * 40];
  __shared__ unsigned short Ps[4][16 * 40];
  const int tid = threadIdx.x;
  const int wave = tid >> 6, lane = tid & 63;
  const int quad = lane >> 4, l16 = lane & 15;
  const int qt = blockIdx.x, h = blockIdx.y, kvh = h >> 2;
  const int t0 = qt * 64;
  const float scale = 0.088388347648318447f;

  for (int e = tid; e < 64 * 16; e += 256) {
    int row = e >> 4, c8 = (e & 15) * 8;
    *(uint4*)&Qs[row * 136 + c8] =
        *(const uint4*)(q + (size_t)(t0 + row) * QDIM + h * DH + c8);
  }

  float m_r[4], l_r[4];
  f32x4 O[8];
#pragma unroll
  for (int r = 0; r < 4; r++) { m_r[r] = -1e30f; l_r[r] = 0.f; }
#pragma unroll
  for (int dt = 0; dt < 8; dt++) O[dt] = f32x4{0.f, 0.f, 0.f, 0.f};

  const int kb_start = (t0 > WIN - 1) ? ((t0 - (WIN - 1)) >> 5) : 0;
  const int kb_end = (t0 + 63) >> 5;

  for (int kb = kb_start; kb <= kb_end; kb++) {
    __syncthreads();
    for (int e = tid; e < 512; e += 256) {
      int row = e >> 4, c8 = (e & 15) * 8;
      *(uint4*)&Ks[row * 136 + c8] =
          *(const uint4*)(kv + (size_t)(kb * 32 + row) * DKV + kvh * DH + c8);
    }
    for (int e = tid; e < 512; e += 256) {
      int row = e >> 2, c8 = (e & 3) * 8;
      *(uint4*)&Vts[row * 40 + c8] =
          *(const uint4*)(vt + (size_t)(kvh * DH + row) * T_SEQ + kb * 32 + c8);
    }
    __syncthreads();

    f32x4 S0 = f32x4{0.f, 0.f, 0.f, 0.f}, S1 = f32x4{0.f, 0.f, 0.f, 0.f};
#pragma unroll
    for (int s = 0; s < 4; s++) {
      bf16x8 a = *(const bf16x8*)&Qs[(wave * 16 + l16) * 136 + s * 32 + quad * 8];
      bf16x8 b0 = *(const bf16x8*)&Ks[(l16) * 136 + s * 32 + quad * 8];
      bf16x8 b1 = *(const bf16x8*)&Ks[(16 + l16) * 136 + s * 32 + quad * 8];
      S0 = __builtin_amdgcn_mfma_f32_16x16x32_bf16(a, b0, S0, 0, 0, 0);
      S1 = __builtin_amdgcn_mfma_f32_16x16x32_bf16(a, b1, S1, 0, 0, 0);
    }

    const int ka0 = kb * 32 + l16;
    const int ka1 = ka0 + 16;
    const bool full = (kb * 32 >= t0 + 63 - (WIN - 1)) && (kb * 32 + 31 <= t0);

    float alpha_r[4];
#pragma unroll
    for (int r = 0; r < 4; r++) {
      int qa = t0 + wave * 16 + quad * 4 + r;
      float v0 = S0[r] * scale, v1 = S1[r] * scale;
      bool x0 = true, x1 = true;
      if (!full) {
        x0 = (ka0 <= qa) && (ka0 > qa - WIN);
        x1 = (ka1 <= qa) && (ka1 > qa - WIN);
        if (!x0) v0 = -1e30f;
        if (!x1) v1 = -1e30f;
      }
      float rm = fmaxf(v0, v1);
      rm = fmaxf(rm, __shfl_xor(rm, 1));
      rm = fmaxf(rm, __shfl_xor(rm, 2));
      rm = fmaxf(rm, __shfl_xor(rm, 4));
      rm = fmaxf(rm, __shfl_xor(rm, 8));
      float mnew = fmaxf(m_r[r], rm);
      float al = __expf(m_r[r] - mnew);
      float p0 = x0 ? __expf(v0 - mnew) : 0.f;
      float p1 = x1 ? __expf(v1 - mnew) : 0.f;
      float rs = p0 + p1;
      rs += __shfl_xor(rs, 1);
      rs += __shfl_xor(rs, 2);
      rs += __shfl_xor(rs, 4);
      rs += __shfl_xor(rs, 8);
      l_r[r] = l_r[r] * al + rs;
      m_r[r] = mnew;
      alpha_r[r] = al;
      Ps[wave][(quad * 4 + r) * 40 + l16]      = f2b_bits(p0);
      Ps[wave][(quad * 4 + r) * 40 + 16 + l16] = f2b_bits(p1);
    }
#pragma unroll
    for (int dt = 0; dt < 8; dt++)
#pragma unroll
      for (int r = 0; r < 4; r++) O[dt][r] *= alpha_r[r];

    bf16x8 pa = *(const bf16x8*)&Ps[wave][l16 * 40 + quad * 8];
#pragma unroll
    for (int dt = 0; dt < 8; dt++) {
      bf16x8 b = *(const bf16x8*)&Vts[(dt * 16 + l16) * 40 + quad * 8];
      O[dt] = __builtin_amdgcn_mfma_f32_16x16x32_bf16(pa, b, O[dt], 0, 0, 0);
    }
  }

  float inv[4];
#pragma unroll
  for (int r = 0; r < 4; r++) inv[r] = 1.f / l_r[r];
#pragma unroll
  for (int dt = 0; dt < 8; dt++)
#pragma unroll
    for (int r = 0; r < 4; r++) {
      int row = t0 + wave * 16 + quad * 4 + r;
      y[(size_t)row * QDIM + h * DH + dt * 16 + l16] = __float2bfloat16(O[dt][r] * inv[r]);
    }
}

// ---------------------------------------------------------------------------
extern "C" void kernel_launch(void* const* d_in, const int* in_sizes, int n_in,
                              void* d_out, int out_size, void* d_ws, size_t ws_size,
                              hipStream_t stream)
{
  const void* x      = d_in[0];
  const void* W_attn = d_in[1];
  const void* A_log  = d_in[2];
  const void* xpw    = d_in[3];
  const void* dtw    = d_in[4];
  const void* dtb    = d_in[5];
  const void* Dp     = d_in[6];
  const void* W_o    = d_in[7];

  // Workspace, TOTAL ~69 MiB:
  char* ws = (char*)d_ws;
  int*   dflag = (int*)ws;   ws += 256;
  bf16*  u     = (bf16*)ws;  ws += (size_t)T_SEQ * DKV * 2;        // 8.4 MB, becomes kv in-place
  float* xd    = (float*)ws; ws += (size_t)T_SEQ * 96 * 4;         // 1.6 MB
  char*  yreg  = ws;                                                // y aliases delta+Pb+Hl (16.78 MB)
  bf16*  delta = (bf16*)ws;  ws += (size_t)T_SEQ * DKV * 2;        // 8.4 MB
  float* Pb    = (float*)ws; ws += (size_t)NCHUNK * DKV * NST * 4; // 4.2 MB (becomes Hin)
  float* Hl    = (float*)ws; ws += (size_t)NCHUNK * DKV * NST * 4; // 4.2 MB
  unsigned short* x_bf  = (unsigned short*)ws; ws += (size_t)T_SEQ * NEMBD * 2;  // 16.8 MB
  unsigned short* wa_bf = (unsigned short*)ws; ws += (size_t)QKVD * NEMBD * 2;   // 12.6 MB
  unsigned short* wo_bf = (unsigned short*)ws; ws += (size_t)NEMBD * QDIM * 2;   //  8.4 MB
  unsigned short* vt    = (unsigned short*)ws; ws += (size_t)KDIM * T_SEQ * 2;   //  4.2 MB
  unsigned short* xpw_bf = (unsigned short*)ws; ws += (size_t)96 * DKV * 2;      //  0.2 MB
  unsigned short* dtw_bf = (unsigned short*)ws; ws += (size_t)DKV * DTR * 2;     //  0.13 MB
  bf16*  y     = (bf16*)yreg;

  bf16*  q_bf = (bf16*)d_out;   // q parks in d_out until gemm2 overwrites it
  float* out  = (float*)d_out;

  detect_dtype<<<1, 64, 0, stream>>>((const unsigned short*)x, dflag);
  cvt_bf16<<<(T_SEQ * NEMBD / 8 + 255) / 256, 256, 0, stream>>>(x, dflag, x_bf, T_SEQ * NEMBD / 8);
  cvt_bf16<<<(QKVD * NEMBD / 8 + 255) / 256, 256, 0, stream>>>(W_attn, dflag, wa_bf, QKVD * NEMBD / 8);
  cvt_bf16<<<(NEMBD * QDIM / 8 + 255) / 256, 256, 0, stream>>>(W_o, dflag, wo_bf, NEMBD * QDIM / 8);
  cvt_bf16<<<(96 * DKV / 8 + 255) / 256, 256, 0, stream>>>(xpw, dflag, xpw_bf, 96 * DKV / 8);
  cvt_bf16<<<(DKV * DTR / 8 + 255) / 256, 256, 0, stream>>>(dtw, dflag, dtw_bf, DKV * DTR / 8);

  gemm_mfma<<<dim3(QKVD / 128, T_SEQ / 128), 256, 0, stream>>>(
      x_bf, wa_bf, T_SEQ, QKVD, NEMBD, 0, q_bf, u, nullptr);
  xdbl_mfma<<<T_SEQ / 64, 256, 0, stream>>>(u, xpw_bf, xd);
  delta_mfma<<<dim3(DKV / 128, T_SEQ / 64), 256, 0, stream>>>(xd, dtw_bf, dtb, dflag, delta);
  scan_pass1<<<4096, 256, 0, stream>>>(delta, u, xd, A_log, dflag, Pb, Hl);
  scan_combine<<<64, 256, 0, stream>>>(Pb, Hl);
  scan_pass2<<<4096, 256, 0, stream>>>(delta, u, xd, A_log, Dp, dflag, Pb);
  vtrans<<<dim3(T_SEQ / 64, KDIM / 64), 256, 0, stream>>>(u, vt);
  attn_mfma<<<dim3(T_SEQ / 64, NH), 256, 0, stream>>>(q_bf, u, vt, y);
  gemm_mfma<<<dim3(QDIM / 128, T_SEQ / 128), 256, 0, stream>>>(
      (const unsigned short*)y, wo_bf, T_SEQ, QDIM, QDIM, 1, nullptr, nullptr, out);
}